// Round 4
// baseline (4139.341 us; speedup 1.0000x reference)
//
#include <hip/hip_runtime.h>

// ---------------------------------------------------------------------------
// Decision-Transformer-like model. bf16-MFMA for dense GEMMs, fp32 elsewhere.
// B=8, L=128, D=512, H=8, DK=64, DFF=2048, NL=6, T=383, SC=14, AC=73
// Round 3: weight GEMMs -> mfma_f32_16x16x32_bf16 (128x128 tile, BK=64).
//          Attention/conv/LN/softmax remain validated fp32 paths.
// ---------------------------------------------------------------------------

#define TT 383

typedef short      bf16x8 __attribute__((ext_vector_type(8)));
typedef float      f32x4  __attribute__((ext_vector_type(4)));
typedef unsigned short u16x8 __attribute__((ext_vector_type(8)));
typedef unsigned short u16x4 __attribute__((ext_vector_type(4)));

// ---------------- fp32 -> bf16 cast (RNE), 4 elems/thread -------------------
__device__ __forceinline__ unsigned short f2bf(float f)
{
  unsigned u = __float_as_uint(f);
  return (unsigned short)((u + 0x7FFFu + ((u >> 16) & 1u)) >> 16);
}

__global__ __launch_bounds__(256) void cast_bf16_kernel(
    const float* __restrict__ in, unsigned short* __restrict__ out, long n)
{
  long i = ((long)blockIdx.x * 256 + threadIdx.x) * 4;
  if (i >= n) return;
  const float4 v = *(const float4*)(in + i);
  u16x4 o;
  o.x = f2bf(v.x); o.y = f2bf(v.y); o.z = f2bf(v.z); o.w = f2bf(v.w);
  *(u16x4*)(out + i) = o;
}

// ---------------- bf16 MFMA GEMM: C = A @ B^T + bias, optional relu ---------
// A: [M,K] bf16 row-major. B: [N,K] bf16 row-major (weights). C: [M,N] fp32.
// Requires: K % 64 == 0, N % 128 == 0. M arbitrary (row-clamped loads).
// Tile 128x128, BK=64, 4 waves (2x2 of 64x64), 16 MFMA 16x16x32 per wave/k-step.
#define LDAP 72   // padded LDS row (shorts): 144 B, multiple of 16 B
__global__ __launch_bounds__(256) void gemm_bf16_kernel(
    const unsigned short* __restrict__ A, const unsigned short* __restrict__ B,
    const float* __restrict__ bias, float* __restrict__ C,
    int M, int N, int K, int relu)
{
  __shared__ __align__(16) unsigned short As[128 * LDAP];
  __shared__ __align__(16) unsigned short Bs[128 * LDAP];

  const int tid = threadIdx.x;
  const int lane = tid & 63;
  const int w  = tid >> 6;                  // wave 0..3
  const int wr = w >> 1, wc = w & 1;        // 2x2 wave grid
  const int m0 = blockIdx.x * 128, n0 = blockIdx.y * 128;

  const int lr = lane & 15;                 // fragment row (A) / col (B/D)
  const int hi = lane >> 4;                 // 0..3

  f32x4 acc[4][4] = {};

  const int r = tid >> 1;                   // staging row 0..127
  const int h = tid & 1;                    // staging half (32 shorts)

  int mrow = m0 + r; if (mrow >= M) mrow = M - 1;   // clamp (rows not stored)
  const unsigned short* Ap = A + (long)mrow * K + h * 32;
  const unsigned short* Bp = B + (long)(n0 + r) * K + h * 32;
  unsigned short* Asd = As + r * LDAP + h * 32;
  unsigned short* Bsd = Bs + r * LDAP + h * 32;

  for (int k0 = 0; k0 < K; k0 += 64) {
#pragma unroll
    for (int i = 0; i < 4; ++i)
      *(u16x8*)(Asd + i * 8) = *(const u16x8*)(Ap + k0 + i * 8);
#pragma unroll
    for (int i = 0; i < 4; ++i)
      *(u16x8*)(Bsd + i * 8) = *(const u16x8*)(Bp + k0 + i * 8);
    __syncthreads();

#pragma unroll
    for (int kk = 0; kk < 2; ++kk) {
      const int kof = kk * 32 + hi * 8;     // same (hi,j)->k map for A and B
      bf16x8 a[4], b[4];
#pragma unroll
      for (int t = 0; t < 4; ++t)
        a[t] = *(const bf16x8*)(As + (wr * 64 + t * 16 + lr) * LDAP + kof);
#pragma unroll
      for (int t = 0; t < 4; ++t)
        b[t] = *(const bf16x8*)(Bs + (wc * 64 + t * 16 + lr) * LDAP + kof);
#pragma unroll
      for (int i = 0; i < 4; ++i)
#pragma unroll
        for (int j = 0; j < 4; ++j)
          acc[i][j] = __builtin_amdgcn_mfma_f32_16x16x32_bf16(a[i], b[j], acc[i][j], 0, 0, 0);
    }
    __syncthreads();
  }

  // C/D layout (HW-verified m89): col = lane&15, row = (lane>>4)*4 + reg
#pragma unroll
  for (int j = 0; j < 4; ++j) {
    const int col = n0 + wc * 64 + j * 16 + lr;
    const float bv = bias ? bias[col] : 0.f;
#pragma unroll
    for (int i = 0; i < 4; ++i) {
#pragma unroll
      for (int v = 0; v < 4; ++v) {
        int row = m0 + wr * 64 + i * 16 + hi * 4 + v;
        if (row < M) {
          float x = acc[i][j][v] + bv;
          if (relu) x = fmaxf(x, 0.f);
          C[(long)row * N + col] = x;
        }
      }
    }
  }
}

static inline void gemm_bf(hipStream_t st, const unsigned short* A, const unsigned short* B,
                           const float* bias, float* C, int M, int N, int K, int relu = 0)
{
  dim3 g((M + 127) / 128, N / 128);
  gemm_bf16_kernel<<<g, 256, 0, st>>>(A, B, bias, C, M, N, K, relu);
}

static inline void cast_bf(hipStream_t st, const float* in, unsigned short* out, long n)
{
  cast_bf16_kernel<<<(int)((n / 4 + 255) / 256), 256, 0, st>>>(in, out, n);
}

// ---------------- fp32 tiled GEMM (attention only) --------------------------
// A: [M,K] (lda). transB=1: B [N,K]; transB=0: B [K,N]. Batched via grid.z.
__global__ __launch_bounds__(256) void gemm_kernel(
    const float* __restrict__ A, const float* __restrict__ B,
    const float* __restrict__ bias, float* __restrict__ C,
    int M, int N, int K, int lda, int ldb, int ldc,
    long sAb, long sAh, long sBb, long sBh, long sCb, long sCh,
    int nH, int transB, int relu)
{
  int bz = blockIdx.z;
  int bb = bz / nH, hh = bz % nH;
  A += (long)bb * sAb + (long)hh * sAh;
  B += (long)bb * sBb + (long)hh * sBh;
  C += (long)bb * sCb + (long)hh * sCh;

  __shared__ float Asf[16][132];
  __shared__ float Bsf[16][68];

  const int tid = threadIdx.x;
  const int tx = tid & 15, ty = tid >> 4;
  const int m0 = blockIdx.x * 128, n0 = blockIdx.y * 64;

  float acc[8][4] = {};

  for (int k0 = 0; k0 < K; k0 += 16) {
    {
      int r  = tid >> 1;
      int kk = (tid & 1) * 8;
      int m  = m0 + r;
#pragma unroll
      for (int i = 0; i < 8; ++i) {
        int k = k0 + kk + i;
        Asf[kk + i][r] = (m < M && k < K) ? A[(long)m * lda + k] : 0.f;
      }
      if (transB) {
        int rn  = tid >> 2;
        int kkb = (tid & 3) << 2;
        int n   = n0 + rn;
#pragma unroll
        for (int i = 0; i < 4; ++i) {
          int k = k0 + kkb + i;
          Bsf[kkb + i][rn] = (n < N && k < K) ? B[(long)n * ldb + k] : 0.f;
        }
      } else {
        int kr = tid >> 4;
        int nc = (tid & 15) << 2;
        int k  = k0 + kr;
#pragma unroll
        for (int i = 0; i < 4; ++i) {
          int n = n0 + nc + i;
          Bsf[kr][nc + i] = (k < K && n < N) ? B[(long)k * ldb + n] : 0.f;
        }
      }
    }
    __syncthreads();
#pragma unroll
    for (int kk = 0; kk < 16; ++kk) {
      float a8[8], b4[4];
#pragma unroll
      for (int i = 0; i < 8; ++i) a8[i] = Asf[kk][ty * 8 + i];
#pragma unroll
      for (int j = 0; j < 4; ++j) b4[j] = Bsf[kk][tx * 4 + j];
#pragma unroll
      for (int i = 0; i < 8; ++i)
#pragma unroll
        for (int j = 0; j < 4; ++j)
          acc[i][j] = fmaf(a8[i], b4[j], acc[i][j]);
    }
    __syncthreads();
  }
#pragma unroll
  for (int i = 0; i < 8; ++i) {
    int m = m0 + ty * 8 + i;
    if (m >= M) continue;
    float* cp = C + (long)m * ldc;
#pragma unroll
    for (int j = 0; j < 4; ++j) {
      int n = n0 + tx * 4 + j;
      if (n >= N) continue;
      float v = acc[i][j];
      if (bias) v += bias[n];
      if (relu) v = fmaxf(v, 0.f);
      cp[n] = v;
    }
  }
}

static inline void gemm(hipStream_t st, const float* A, const float* B,
                        const float* bias, float* C,
                        int M, int N, int K, int lda, int ldb, int ldc,
                        long sAb = 0, long sAh = 0, long sBb = 0, long sBh = 0,
                        long sCb = 0, long sCh = 0,
                        int nH = 1, int nBatch = 1, int transB = 1, int relu = 0)
{
  dim3 g((M + 127) / 128, (N + 63) / 64, nBatch);
  gemm_kernel<<<g, 256, 0, st>>>(A, B, bias, C, M, N, K, lda, ldb, ldc,
                                 sAb, sAh, sBb, sBh, sCb, sCh, nH, transB, relu);
}

// ---------------- direct 3x3 conv (pad 1, 8x8, relu) ------------------------
template <int CIN>
__global__ __launch_bounds__(256) void conv3x3_kernel(
    const float* __restrict__ in, const float* __restrict__ w,
    const float* __restrict__ bias, float* __restrict__ out, int Cout)
{
  __shared__ float img[CIN * 100]; // [ic][10][10], zero-padded border
  const int n = blockIdx.x;
  const int tid = threadIdx.x;
  for (int i = tid; i < CIN * 100; i += 256) img[i] = 0.f;
  __syncthreads();
  const float* src = in + (long)n * CIN * 64;
  for (int i = tid; i < CIN * 64; i += 256) {
    int ic = i >> 6, p = i & 63;
    img[ic * 100 + ((p >> 3) + 1) * 10 + (p & 7) + 1] = src[i];
  }
  __syncthreads();

  const int y  = tid & 7;
  const int oc = blockIdx.y * 32 + (tid >> 3);
  if (oc >= Cout) return;

  float acc[8];
#pragma unroll
  for (int x = 0; x < 8; ++x) acc[x] = bias[oc];

  const float* wp = w + (long)oc * CIN * 9;
  for (int ic = 0; ic < CIN; ++ic) {
    float wr[9];
#pragma unroll
    for (int q = 0; q < 9; ++q) wr[q] = wp[ic * 9 + q];
    const float* ib = &img[ic * 100 + y * 10];
#pragma unroll
    for (int ky = 0; ky < 3; ++ky) {
      const float* r = ib + ky * 10;
      float c0 = r[0], c1 = r[1];
#pragma unroll
      for (int x = 0; x < 8; ++x) {
        float c2 = r[x + 2];
        acc[x] = fmaf(c0, wr[ky * 3 + 0],
                 fmaf(c1, wr[ky * 3 + 1],
                 fmaf(c2, wr[ky * 3 + 2], acc[x])));
        c0 = c1; c1 = c2;
      }
    }
  }
  float* dst = out + ((long)n * Cout + oc) * 64 + y * 8;
#pragma unroll
  for (int x = 0; x < 8; ++x) dst[x] = fmaxf(acc[x], 0.f);
}

// ---------------- transposed conv (gather form) -----------------------------
__global__ __launch_bounds__(256) void convT_kernel(
    const float* __restrict__ in, const float* __restrict__ w,
    const float* __restrict__ bias, float* __restrict__ out,
    int Cin, int Cout, int IH, int OH, int s, int relu)
{
  __shared__ float img[2048];
  const int n = blockIdx.x;
  const int tid = threadIdx.x;
  const int isz = Cin * IH * IH;
  const float* src = in + (long)n * isz;
  for (int i = tid; i < isz; i += 256) img[i] = src[i];
  __syncthreads();

  const int total = Cout * OH * OH;
  for (int o = tid; o < total; o += 256) {
    int oc = o / (OH * OH);
    int p  = o % (OH * OH);
    int oy = p / OH, ox = p % OH;
    float acc = bias[oc];
#pragma unroll
    for (int ky = 0; ky < 3; ++ky) {
      int py = oy + ky - 1;
      if (py < 0 || (py % s) || (py / s) >= IH) continue;
      int iy = py / s;
#pragma unroll
      for (int kx = 0; kx < 3; ++kx) {
        int px = ox + kx - 1;
        if (px < 0 || (px % s) || (px / s) >= IH) continue;
        int ix = px / s;
        int wi = (2 - ky) * 3 + (2 - kx);
        const float* ib = img + iy * IH + ix;
        const float* wb = w + (long)oc * 9 + wi;
        for (int ic = 0; ic < Cin; ++ic)
          acc = fmaf(ib[ic * IH * IH], wb[(long)ic * Cout * 9], acc);
      }
    }
    if (relu) acc = fmaxf(acc, 0.f);
    out[(long)n * total + o] = acc;
  }
}

// ---------------- LayerNorm (D=512), optional residual add ------------------
__device__ __forceinline__ float blockReduceSum256(float v)
{
  __shared__ float sb[4];
  int lane = threadIdx.x & 63, wid = threadIdx.x >> 6;
#pragma unroll
  for (int o = 32; o; o >>= 1) v += __shfl_down(v, o);
  __syncthreads();
  if (lane == 0) sb[wid] = v;
  __syncthreads();
  return sb[0] + sb[1] + sb[2] + sb[3];
}

__global__ __launch_bounds__(256) void add_ln_kernel(
    const float* __restrict__ a, const float* __restrict__ b,
    const float* __restrict__ w, const float* __restrict__ bb,
    float* __restrict__ out)
{
  long row = blockIdx.x;
  const float* pa = a + row * 512;
  float x0 = pa[threadIdx.x], x1 = pa[threadIdx.x + 256];
  if (b) {
    const float* pb = b + row * 512;
    x0 += pb[threadIdx.x]; x1 += pb[threadIdx.x + 256];
  }
  float mean = blockReduceSum256(x0 + x1) * (1.f / 512.f);
  float d0 = x0 - mean, d1 = x1 - mean;
  float var = blockReduceSum256(d0 * d0 + d1 * d1) * (1.f / 512.f);
  float inv = 1.0f / sqrtf(var + 1e-5f);
  float* po = out + row * 512;
  po[threadIdx.x]       = d0 * inv * w[threadIdx.x] + bb[threadIdx.x];
  po[threadIdx.x + 256] = d1 * inv * w[threadIdx.x + 256] + bb[threadIdx.x + 256];
}

// ---------------- causal softmax over scores [64, T, T] ---------------------
__global__ __launch_bounds__(256) void softmax_kernel(float* __restrict__ sc, float scale)
{
  long row = (long)blockIdx.x * 4 + (threadIdx.x >> 6);
  int lane = threadIdx.x & 63;
  if (row >= (long)64 * TT) return;
  int q = (int)(row % TT);
  float* p = sc + row * TT;
  int len = q + 1;
  float mx = -1e30f;
  for (int j = lane; j < len; j += 64) mx = fmaxf(mx, p[j] * scale);
#pragma unroll
  for (int o = 32; o; o >>= 1) mx = fmaxf(mx, __shfl_xor(mx, o));
  float sum = 0.f;
  for (int j = lane; j < len; j += 64) {
    float e = expf(p[j] * scale - mx);
    p[j] = e;
    sum += e;
  }
#pragma unroll
  for (int o = 32; o; o >>= 1) sum += __shfl_xor(sum, o);
  float inv = 1.0f / sum;
  for (int j = lane; j < TT; j += 64) p[j] = (j < len) ? p[j] * inv : 0.f;
}

// ---------------- small elementwise kernels ---------------------------------
__global__ void lin1_relu_kernel(const float* __restrict__ x, const float* __restrict__ w,
                                 const float* __restrict__ b, float* __restrict__ out, long total)
{
  long idx = (long)blockIdx.x * 256 + threadIdx.x;
  if (idx >= total) return;
  int d = idx & 511; long r = idx >> 9;
  out[idx] = fmaxf(fmaf(x[r], w[d], b[d]), 0.f);
}

__global__ void lin1_relu_int_kernel(const int* __restrict__ x, const float* __restrict__ w,
                                     const float* __restrict__ b, float* __restrict__ out, long total)
{
  long idx = (long)blockIdx.x * 256 + threadIdx.x;
  if (idx >= total) return;
  int d = idx & 511; long r = idx >> 9;
  out[idx] = fmaxf(fmaf((float)x[r], w[d], b[d]), 0.f);
}

__global__ void build_comb_kernel(const float* __restrict__ r, const float* __restrict__ s,
                                  const float* __restrict__ a, const float* __restrict__ t,
                                  float* __restrict__ comb)
{
  long idx = (long)blockIdx.x * 256 + threadIdx.x;
  if (idx >= (long)8 * TT * 512) return;
  int d = idx & 511;
  long rr = idx >> 9;
  int tok = (int)(rr % TT);
  int b   = (int)(rr / TT);
  int grp = tok / 3, ph = tok % 3;
  float te = t[((long)b * 128 + grp) * 512 + d];
  float v;
  if (ph == 0)      v = r[((long)b * 128 + grp) * 512 + d] + te;
  else if (ph == 1) v = s[((long)b * 128 + grp) * 512 + d] + te;
  else              v = a[((long)b * 127 + grp) * 512 + d] + te;
  comb[idx] = v;
}

__global__ void gather3_kernel(const float* __restrict__ x, float* __restrict__ out,
                               int offset, int count)
{
  long idx = (long)blockIdx.x * 256 + threadIdx.x;
  long total = (long)8 * count * 512;
  if (idx >= total) return;
  int d = idx & 511;
  long r = idx >> 9;
  int i = (int)(r % count);
  int b = (int)(r / count);
  out[idx] = x[((long)b * TT + offset + 3 * i) * 512 + d];
}

__global__ __launch_bounds__(256) void reward_kernel(const float* __restrict__ x,
                                                     const float* __restrict__ w,
                                                     const float* __restrict__ b,
                                                     float* __restrict__ out, int rows)
{
  int row = blockIdx.x * 4 + (threadIdx.x >> 6);
  int lane = threadIdx.x & 63;
  if (row >= rows) return;
  const float* p = x + (long)row * 512;
  float s = 0.f;
  for (int j = lane; j < 512; j += 64) s = fmaf(p[j], w[j], s);
#pragma unroll
  for (int o = 32; o; o >>= 1) s += __shfl_xor(s, o);
  if (lane == 0) out[row] = s + b[0];
}

// ---------------------------------------------------------------------------
extern "C" void kernel_launch(void* const* d_in, const int* in_sizes, int n_in,
                              void* d_out, int out_size, void* d_ws, size_t ws_size,
                              hipStream_t stream)
{
  const float* states  = (const float*)d_in[0];
  const float* rtgs    = (const float*)d_in[1];
  const int*   tsteps  = (const int*)d_in[2];
  const float* actions = (const float*)d_in[3];
  // d_in[4] mask: tril, hardcoded causal
  const float* se_c1w = (const float*)d_in[5];  const float* se_c1b = (const float*)d_in[6];
  const float* se_c2w = (const float*)d_in[7];  const float* se_c2b = (const float*)d_in[8];
  const float* se_c3w = (const float*)d_in[9];  const float* se_c3b = (const float*)d_in[10];
  const float* se_fcw = (const float*)d_in[11]; const float* se_fcb = (const float*)d_in[12];
  const float* se_lnw = (const float*)d_in[13]; const float* se_lnb = (const float*)d_in[14];
  const float* ae_c1w = (const float*)d_in[15]; const float* ae_c1b = (const float*)d_in[16];
  const float* ae_c2w = (const float*)d_in[17]; const float* ae_c2b = (const float*)d_in[18];
  const float* ae_c3w = (const float*)d_in[19]; const float* ae_c3b = (const float*)d_in[20];
  const float* ae_fcw = (const float*)d_in[21]; const float* ae_fcb = (const float*)d_in[22];
  const float* ae_lnw = (const float*)d_in[23]; const float* ae_lnb = (const float*)d_in[24];
  const float* rtg_w1 = (const float*)d_in[25]; const float* rtg_b1 = (const float*)d_in[26];
  const float* rtg_w2 = (const float*)d_in[27]; const float* rtg_b2 = (const float*)d_in[28];
  const float* rtg_lnw= (const float*)d_in[29]; const float* rtg_lnb= (const float*)d_in[30];
  const float* ts_w1  = (const float*)d_in[31]; const float* ts_b1  = (const float*)d_in[32];
  const float* ts_w2  = (const float*)d_in[33]; const float* ts_b2  = (const float*)d_in[34];
  const float* ts_lnw = (const float*)d_in[35]; const float* ts_lnb = (const float*)d_in[36];
  const float* ip_w   = (const float*)d_in[37]; const float* ip_b   = (const float*)d_in[38];
  const float* lyr_wq = (const float*)d_in[39]; const float* lyr_bq = (const float*)d_in[40];
  const float* lyr_wk = (const float*)d_in[41]; const float* lyr_bk = (const float*)d_in[42];
  const float* lyr_wv = (const float*)d_in[43]; const float* lyr_bv = (const float*)d_in[44];
  const float* lyr_wo = (const float*)d_in[45]; const float* lyr_bo = (const float*)d_in[46];
  const float* lyr_f1w= (const float*)d_in[47]; const float* lyr_f1b= (const float*)d_in[48];
  const float* lyr_f2w= (const float*)d_in[49]; const float* lyr_f2b= (const float*)d_in[50];
  const float* lyr_l1w= (const float*)d_in[51]; const float* lyr_l1b= (const float*)d_in[52];
  const float* lyr_l2w= (const float*)d_in[53]; const float* lyr_l2b= (const float*)d_in[54];
  const float* ad_fcw = (const float*)d_in[55]; const float* ad_fcb = (const float*)d_in[56];
  const float* ad_w1  = (const float*)d_in[57]; const float* ad_b1  = (const float*)d_in[58];
  const float* ad_w2  = (const float*)d_in[59]; const float* ad_b2  = (const float*)d_in[60];
  const float* ad_w3  = (const float*)d_in[61]; const float* ad_b3  = (const float*)d_in[62];
  const float* sd_fcw = (const float*)d_in[63]; const float* sd_fcb = (const float*)d_in[64];
  const float* sd_w1  = (const float*)d_in[65]; const float* sd_b1  = (const float*)d_in[66];
  const float* sd_w2  = (const float*)d_in[67]; const float* sd_b2  = (const float*)d_in[68];
  const float* sd_w3  = (const float*)d_in[69]; const float* sd_b3  = (const float*)d_in[70];
  const float* rp_w   = (const float*)d_in[71]; const float* rp_b   = (const float*)d_in[72];

  float* ws = (float*)d_ws;
  long off = 0;
  auto alloc = [&](long n) { float* p = ws + off; off += n; return p; };

  float* region = alloc(10485760);          // conv bufs / scores / decoder bufs
  float* h1 = region;                        // 1024*32*64
  float* h2 = region + 2097152;              // 1024*64*64
  float* h3 = region + 6291456;              // 1024*64*64
  float* scores = region;                    // 64*383*383 = 9,388,096
  float* s_emb = alloc(524288);
  float* a_emb = alloc(520192);
  float* r_emb = alloc(524288);
  float* t_emb = alloc(524288);
  float* etmp  = alloc(524288);
  float* xa = alloc(1568768);
  float* xb = alloc(1568768);
  float* qb = alloc(1568768);
  float* kb = alloc(1568768);
  float* vb = alloc(1568768);
  float* ao = alloc(1568768);
  float* t2 = alloc(1568768);
  float* ffh = alloc(6275072);

  // bf16 region (ushort) after the float region
  unsigned short* bws = (unsigned short*)(ws + off);
  long boff = 0;
  auto ballo = [&](long n) { unsigned short* p = bws + boff; boff += n; return p; };
  unsigned short* ipW  = ballo(262144);
  unsigned short* wqW  = ballo(6L * 262144);
  unsigned short* wkW  = ballo(6L * 262144);
  unsigned short* wvW  = ballo(6L * 262144);
  unsigned short* woW  = ballo(6L * 262144);
  unsigned short* f1W  = ballo(6L * 1048576);
  unsigned short* f2W  = ballo(6L * 1048576);
  unsigned short* seW  = ballo(2097152);
  unsigned short* aeW  = ballo(2097152);
  unsigned short* rtgW = ballo(262144);
  unsigned short* tsW  = ballo(262144);
  unsigned short* adW  = ballo(262144);
  unsigned short* sdW  = ballo(262144);
  unsigned short* abuf = ballo(6275072);     // activation cast scratch

  const long T2 = (long)TT * TT;             // 146689
  const long BT = (long)8 * TT;              // 3064

  // ---------------- weight pre-casts (fp32 -> bf16) ----------------
  cast_bf(stream, ip_w,    ipW,  262144);
  cast_bf(stream, lyr_wq,  wqW,  6L * 262144);
  cast_bf(stream, lyr_wk,  wkW,  6L * 262144);
  cast_bf(stream, lyr_wv,  wvW,  6L * 262144);
  cast_bf(stream, lyr_wo,  woW,  6L * 262144);
  cast_bf(stream, lyr_f1w, f1W,  6L * 1048576);
  cast_bf(stream, lyr_f2w, f2W,  6L * 1048576);
  cast_bf(stream, se_fcw,  seW,  2097152);
  cast_bf(stream, ae_fcw,  aeW,  2097152);
  cast_bf(stream, rtg_w2,  rtgW, 262144);
  cast_bf(stream, ts_w2,   tsW,  262144);
  cast_bf(stream, ad_fcw,  adW,  262144);
  cast_bf(stream, sd_fcw,  sdW,  262144);

  // ---------------- encoders ----------------
  // state CNN (1024 images)
  conv3x3_kernel<14><<<dim3(1024, 1), 256, 0, stream>>>(states, se_c1w, se_c1b, h1, 32);
  conv3x3_kernel<32><<<dim3(1024, 2), 256, 0, stream>>>(h1, se_c2w, se_c2b, h2, 64);
  conv3x3_kernel<64><<<dim3(1024, 2), 256, 0, stream>>>(h2, se_c3w, se_c3b, h3, 64);
  cast_bf(stream, h3, abuf, 1024L * 4096);
  gemm_bf(stream, abuf, seW, se_fcb, etmp, 1024, 512, 4096);
  add_ln_kernel<<<1024, 256, 0, stream>>>(etmp, nullptr, se_lnw, se_lnb, s_emb);

  // action CNN (1016 images)
  conv3x3_kernel<73><<<dim3(1016, 1), 256, 0, stream>>>(actions, ae_c1w, ae_c1b, h1, 32);
  conv3x3_kernel<32><<<dim3(1016, 2), 256, 0, stream>>>(h1, ae_c2w, ae_c2b, h2, 64);
  conv3x3_kernel<64><<<dim3(1016, 2), 256, 0, stream>>>(h2, ae_c3w, ae_c3b, h3, 64);
  cast_bf(stream, h3, abuf, 1016L * 4096);
  gemm_bf(stream, abuf, aeW, ae_fcb, etmp, 1016, 512, 4096);
  add_ln_kernel<<<1016, 256, 0, stream>>>(etmp, nullptr, ae_lnw, ae_lnb, a_emb);

  // rtg MLP (1024 rows)
  lin1_relu_kernel<<<(1024 * 512 + 255) / 256, 256, 0, stream>>>(rtgs, rtg_w1, rtg_b1, qb, 1024 * 512);
  cast_bf(stream, qb, abuf, 1024L * 512);
  gemm_bf(stream, abuf, rtgW, rtg_b2, etmp, 1024, 512, 512);
  add_ln_kernel<<<1024, 256, 0, stream>>>(etmp, nullptr, rtg_lnw, rtg_lnb, r_emb);

  // timestep MLP (1024 rows)
  lin1_relu_int_kernel<<<(1024 * 512 + 255) / 256, 256, 0, stream>>>(tsteps, ts_w1, ts_b1, qb, 1024 * 512);
  cast_bf(stream, qb, abuf, 1024L * 512);
  gemm_bf(stream, abuf, tsW, ts_b2, etmp, 1024, 512, 512);
  add_ln_kernel<<<1024, 256, 0, stream>>>(etmp, nullptr, ts_lnw, ts_lnb, t_emb);

  // interleave + input projection
  build_comb_kernel<<<(int)((8L * TT * 512 + 255) / 256), 256, 0, stream>>>(r_emb, s_emb, a_emb, t_emb, xb);
  cast_bf(stream, xb, abuf, BT * 512);
  gemm_bf(stream, abuf, ipW, ip_b, xa, (int)BT, 512, 512);

  // ---------------- transformer layers ----------------
  for (int l = 0; l < 6; ++l) {
    const unsigned short* wq = wqW + (long)l * 262144; const float* bq = lyr_bq + (long)l * 512;
    const unsigned short* wk = wkW + (long)l * 262144; const float* bk = lyr_bk + (long)l * 512;
    const unsigned short* wv = wvW + (long)l * 262144; const float* bv = lyr_bv + (long)l * 512;
    const unsigned short* wo = woW + (long)l * 262144; const float* bo = lyr_bo + (long)l * 512;
    const unsigned short* f1w = f1W + (long)l * 1048576; const float* f1b = lyr_f1b + (long)l * 2048;
    const unsigned short* f2w = f2W + (long)l * 1048576; const float* f2b = lyr_f2b + (long)l * 512;
    const float* l1w = lyr_l1w + (long)l * 512; const float* l1b = lyr_l1b + (long)l * 512;
    const float* l2w = lyr_l2w + (long)l * 512; const float* l2b = lyr_l2b + (long)l * 512;

    cast_bf(stream, xa, abuf, BT * 512);
    gemm_bf(stream, abuf, wq, bq, qb, (int)BT, 512, 512);
    gemm_bf(stream, abuf, wk, bk, kb, (int)BT, 512, 512);
    gemm_bf(stream, abuf, wv, bv, vb, (int)BT, 512, 512);

    // scores[b,h] = Q[b,:,h*64:] @ K[b,:,h*64:]^T   (M=N=383, K=64)  [fp32]
    gemm(stream, qb, kb, nullptr, scores, TT, TT, 64, 512, 512, TT,
         (long)TT * 512, 64, (long)TT * 512, 64, 8 * T2, T2, 8, 64, 1, 0);
    softmax_kernel<<<6128, 256, 0, stream>>>(scores, 0.125f);
    // attout[b,:,h*64:] = P[b,h] @ V[b,:,h*64:]     (M=383, N=64, K=383) [fp32]
    gemm(stream, scores, vb, nullptr, ao, TT, 64, TT, TT, 512, 512,
         8 * T2, T2, (long)TT * 512, 64, (long)TT * 512, 64, 8, 64, 0, 0);

    cast_bf(stream, ao, abuf, BT * 512);
    gemm_bf(stream, abuf, wo, bo, t2, (int)BT, 512, 512);
    add_ln_kernel<<<(int)BT, 256, 0, stream>>>(xa, t2, l1w, l1b, xb);
    cast_bf(stream, xb, abuf, BT * 512);
    gemm_bf(stream, abuf, f1w, f1b, ffh, (int)BT, 2048, 512, 1);   // relu
    cast_bf(stream, ffh, abuf, BT * 2048);
    gemm_bf(stream, abuf, f2w, f2b, t2, (int)BT, 512, 2048);
    add_ln_kernel<<<(int)BT, 256, 0, stream>>>(xb, t2, l2w, l2b, xa);
  }

  // ---------------- decoders ----------------
  float* outp = (float*)d_out;
  float* act_out = outp;              // 8*128*73*64 = 4,784,128
  float* st_out  = outp + 4784128;    // 8*128*14*64 = 917,504
  float* rw_out  = outp + 5701632;    // 8*127 = 1016

  float* za  = region;                // 524288
  float* zfc = region + 524288;       // 524288
  float* dh1 = region + 1048576;      // 1024*64*16
  float* dh2 = region + 2097152;      // 1024*32*64

  // action decoder reads x[:,1::3]
  gather3_kernel<<<(1024 * 512 + 255) / 256, 256, 0, stream>>>(xa, za, 1, 128);
  cast_bf(stream, za, abuf, 1024L * 512);
  gemm_bf(stream, abuf, adW, ad_fcb, zfc, 1024, 512, 512, 1);      // relu
  convT_kernel<<<1024, 256, 0, stream>>>(zfc, ad_w1, ad_b1, dh1, 128, 64, 2, 4, 2, 1);
  convT_kernel<<<1024, 256, 0, stream>>>(dh1, ad_w2, ad_b2, dh2, 64, 32, 4, 8, 2, 1);
  convT_kernel<<<1024, 256, 0, stream>>>(dh2, ad_w3, ad_b3, act_out, 32, 73, 8, 8, 1, 0);

  // state decoder reads x[:,0::3]
  gather3_kernel<<<(1024 * 512 + 255) / 256, 256, 0, stream>>>(xa, za, 0, 128);
  cast_bf(stream, za, abuf, 1024L * 512);
  gemm_bf(stream, abuf, sdW, sd_fcb, zfc, 1024, 512, 512, 1);      // relu
  convT_kernel<<<1024, 256, 0, stream>>>(zfc, sd_w1, sd_b1, dh1, 128, 64, 2, 4, 2, 1);
  convT_kernel<<<1024, 256, 0, stream>>>(dh1, sd_w2, sd_b2, dh2, 64, 32, 4, 8, 2, 1);
  convT_kernel<<<1024, 256, 0, stream>>>(dh2, sd_w3, sd_b3, st_out, 32, 14, 8, 8, 1, 0);

  // reward head reads x[:,2::3] (127 tokens)
  gather3_kernel<<<(1016 * 512 + 255) / 256, 256, 0, stream>>>(xa, za, 2, 127);
  reward_kernel<<<(1016 + 3) / 4, 256, 0, stream>>>(za, rp_w, rp_b, rw_out, 1016);
}

// Round 5
// 3256.361 us; speedup vs baseline: 1.2712x; 1.2712x over previous
//
#include <hip/hip_runtime.h>

// ---------------------------------------------------------------------------
// Decision-Transformer-like model. bf16-MFMA for dense GEMMs, fp32 elsewhere.
// B=8, L=128, D=512, H=8, DK=64, DFF=2048, NL=6, T=383, SC=14, AC=73
// Round 5: convT -> dilated-conv3x3 in LDS (was 287us/dispatch, 1 FMA per
//          strided global weight load; now conv3x3 structure, 8:1 FMA:load).
// ---------------------------------------------------------------------------

#define TT 383

typedef short      bf16x8 __attribute__((ext_vector_type(8)));
typedef float      f32x4  __attribute__((ext_vector_type(4)));
typedef unsigned short u16x8 __attribute__((ext_vector_type(8)));
typedef unsigned short u16x4 __attribute__((ext_vector_type(4)));

// ---------------- fp32 -> bf16 cast (RNE), 4 elems/thread -------------------
__device__ __forceinline__ unsigned short f2bf(float f)
{
  unsigned u = __float_as_uint(f);
  return (unsigned short)((u + 0x7FFFu + ((u >> 16) & 1u)) >> 16);
}

__global__ __launch_bounds__(256) void cast_bf16_kernel(
    const float* __restrict__ in, unsigned short* __restrict__ out, long n)
{
  long i = ((long)blockIdx.x * 256 + threadIdx.x) * 4;
  if (i >= n) return;
  const float4 v = *(const float4*)(in + i);
  u16x4 o;
  o.x = f2bf(v.x); o.y = f2bf(v.y); o.z = f2bf(v.z); o.w = f2bf(v.w);
  *(u16x4*)(out + i) = o;
}

// ---------------- bf16 MFMA GEMM: C = A @ B^T + bias, optional relu ---------
// A: [M,K] bf16 row-major. B: [N,K] bf16 row-major (weights). C: [M,N] fp32.
// Requires: K % 64 == 0, N % 128 == 0. M arbitrary (row-clamped loads).
// Tile 128x128, BK=64, 4 waves (2x2 of 64x64), 16 MFMA 16x16x32 per wave/k-step.
#define LDAP 72   // padded LDS row (shorts): 144 B, multiple of 16 B
__global__ __launch_bounds__(256) void gemm_bf16_kernel(
    const unsigned short* __restrict__ A, const unsigned short* __restrict__ B,
    const float* __restrict__ bias, float* __restrict__ C,
    int M, int N, int K, int relu)
{
  __shared__ __align__(16) unsigned short As[128 * LDAP];
  __shared__ __align__(16) unsigned short Bs[128 * LDAP];

  const int tid = threadIdx.x;
  const int lane = tid & 63;
  const int w  = tid >> 6;                  // wave 0..3
  const int wr = w >> 1, wc = w & 1;        // 2x2 wave grid
  const int m0 = blockIdx.x * 128, n0 = blockIdx.y * 128;

  const int lr = lane & 15;                 // fragment row (A) / col (B/D)
  const int hi = lane >> 4;                 // 0..3

  f32x4 acc[4][4] = {};

  const int r = tid >> 1;                   // staging row 0..127
  const int h = tid & 1;                    // staging half (32 shorts)

  int mrow = m0 + r; if (mrow >= M) mrow = M - 1;   // clamp (rows not stored)
  const unsigned short* Ap = A + (long)mrow * K + h * 32;
  const unsigned short* Bp = B + (long)(n0 + r) * K + h * 32;
  unsigned short* Asd = As + r * LDAP + h * 32;
  unsigned short* Bsd = Bs + r * LDAP + h * 32;

  for (int k0 = 0; k0 < K; k0 += 64) {
#pragma unroll
    for (int i = 0; i < 4; ++i)
      *(u16x8*)(Asd + i * 8) = *(const u16x8*)(Ap + k0 + i * 8);
#pragma unroll
    for (int i = 0; i < 4; ++i)
      *(u16x8*)(Bsd + i * 8) = *(const u16x8*)(Bp + k0 + i * 8);
    __syncthreads();

#pragma unroll
    for (int kk = 0; kk < 2; ++kk) {
      const int kof = kk * 32 + hi * 8;     // same (hi,j)->k map for A and B
      bf16x8 a[4], b[4];
#pragma unroll
      for (int t = 0; t < 4; ++t)
        a[t] = *(const bf16x8*)(As + (wr * 64 + t * 16 + lr) * LDAP + kof);
#pragma unroll
      for (int t = 0; t < 4; ++t)
        b[t] = *(const bf16x8*)(Bs + (wc * 64 + t * 16 + lr) * LDAP + kof);
#pragma unroll
      for (int i = 0; i < 4; ++i)
#pragma unroll
        for (int j = 0; j < 4; ++j)
          acc[i][j] = __builtin_amdgcn_mfma_f32_16x16x32_bf16(a[i], b[j], acc[i][j], 0, 0, 0);
    }
    __syncthreads();
  }

  // C/D layout (HW-verified m89): col = lane&15, row = (lane>>4)*4 + reg
#pragma unroll
  for (int j = 0; j < 4; ++j) {
    const int col = n0 + wc * 64 + j * 16 + lr;
    const float bv = bias ? bias[col] : 0.f;
#pragma unroll
    for (int i = 0; i < 4; ++i) {
#pragma unroll
      for (int v = 0; v < 4; ++v) {
        int row = m0 + wr * 64 + i * 16 + hi * 4 + v;
        if (row < M) {
          float x = acc[i][j][v] + bv;
          if (relu) x = fmaxf(x, 0.f);
          C[(long)row * N + col] = x;
        }
      }
    }
  }
}

static inline void gemm_bf(hipStream_t st, const unsigned short* A, const unsigned short* B,
                           const float* bias, float* C, int M, int N, int K, int relu = 0)
{
  dim3 g((M + 127) / 128, N / 128);
  gemm_bf16_kernel<<<g, 256, 0, st>>>(A, B, bias, C, M, N, K, relu);
}

static inline void cast_bf(hipStream_t st, const float* in, unsigned short* out, long n)
{
  cast_bf16_kernel<<<(int)((n / 4 + 255) / 256), 256, 0, st>>>(in, out, n);
}

// ---------------- fp32 tiled GEMM (attention only) --------------------------
// A: [M,K] (lda). transB=1: B [N,K]; transB=0: B [K,N]. Batched via grid.z.
__global__ __launch_bounds__(256) void gemm_kernel(
    const float* __restrict__ A, const float* __restrict__ B,
    const float* __restrict__ bias, float* __restrict__ C,
    int M, int N, int K, int lda, int ldb, int ldc,
    long sAb, long sAh, long sBb, long sBh, long sCb, long sCh,
    int nH, int transB, int relu)
{
  int bz = blockIdx.z;
  int bb = bz / nH, hh = bz % nH;
  A += (long)bb * sAb + (long)hh * sAh;
  B += (long)bb * sBb + (long)hh * sBh;
  C += (long)bb * sCb + (long)hh * sCh;

  __shared__ float Asf[16][132];
  __shared__ float Bsf[16][68];

  const int tid = threadIdx.x;
  const int tx = tid & 15, ty = tid >> 4;
  const int m0 = blockIdx.x * 128, n0 = blockIdx.y * 64;

  float acc[8][4] = {};

  for (int k0 = 0; k0 < K; k0 += 16) {
    {
      int r  = tid >> 1;
      int kk = (tid & 1) * 8;
      int m  = m0 + r;
#pragma unroll
      for (int i = 0; i < 8; ++i) {
        int k = k0 + kk + i;
        Asf[kk + i][r] = (m < M && k < K) ? A[(long)m * lda + k] : 0.f;
      }
      if (transB) {
        int rn  = tid >> 2;
        int kkb = (tid & 3) << 2;
        int n   = n0 + rn;
#pragma unroll
        for (int i = 0; i < 4; ++i) {
          int k = k0 + kkb + i;
          Bsf[kkb + i][rn] = (n < N && k < K) ? B[(long)n * ldb + k] : 0.f;
        }
      } else {
        int kr = tid >> 4;
        int nc = (tid & 15) << 2;
        int k  = k0 + kr;
#pragma unroll
        for (int i = 0; i < 4; ++i) {
          int n = n0 + nc + i;
          Bsf[kr][nc + i] = (k < K && n < N) ? B[(long)k * ldb + n] : 0.f;
        }
      }
    }
    __syncthreads();
#pragma unroll
    for (int kk = 0; kk < 16; ++kk) {
      float a8[8], b4[4];
#pragma unroll
      for (int i = 0; i < 8; ++i) a8[i] = Asf[kk][ty * 8 + i];
#pragma unroll
      for (int j = 0; j < 4; ++j) b4[j] = Bsf[kk][tx * 4 + j];
#pragma unroll
      for (int i = 0; i < 8; ++i)
#pragma unroll
        for (int j = 0; j < 4; ++j)
          acc[i][j] = fmaf(a8[i], b4[j], acc[i][j]);
    }
    __syncthreads();
  }
#pragma unroll
  for (int i = 0; i < 8; ++i) {
    int m = m0 + ty * 8 + i;
    if (m >= M) continue;
    float* cp = C + (long)m * ldc;
#pragma unroll
    for (int j = 0; j < 4; ++j) {
      int n = n0 + tx * 4 + j;
      if (n >= N) continue;
      float v = acc[i][j];
      if (bias) v += bias[n];
      if (relu) v = fmaxf(v, 0.f);
      cp[n] = v;
    }
  }
}

static inline void gemm(hipStream_t st, const float* A, const float* B,
                        const float* bias, float* C,
                        int M, int N, int K, int lda, int ldb, int ldc,
                        long sAb = 0, long sAh = 0, long sBb = 0, long sBh = 0,
                        long sCb = 0, long sCh = 0,
                        int nH = 1, int nBatch = 1, int transB = 1, int relu = 0)
{
  dim3 g((M + 127) / 128, (N + 63) / 64, nBatch);
  gemm_kernel<<<g, 256, 0, st>>>(A, B, bias, C, M, N, K, lda, ldb, ldc,
                                 sAb, sAh, sBb, sBh, sCb, sCh, nH, transB, relu);
}

// ---------------- direct 3x3 conv (pad 1, 8x8, relu) ------------------------
template <int CIN>
__global__ __launch_bounds__(256) void conv3x3_kernel(
    const float* __restrict__ in, const float* __restrict__ w,
    const float* __restrict__ bias, float* __restrict__ out, int Cout)
{
  __shared__ float img[CIN * 100]; // [ic][10][10], zero-padded border
  const int n = blockIdx.x;
  const int tid = threadIdx.x;
  for (int i = tid; i < CIN * 100; i += 256) img[i] = 0.f;
  __syncthreads();
  const float* src = in + (long)n * CIN * 64;
  for (int i = tid; i < CIN * 64; i += 256) {
    int ic = i >> 6, p = i & 63;
    img[ic * 100 + ((p >> 3) + 1) * 10 + (p & 7) + 1] = src[i];
  }
  __syncthreads();

  const int y  = tid & 7;
  const int oc = blockIdx.y * 32 + (tid >> 3);
  if (oc >= Cout) return;

  float acc[8];
#pragma unroll
  for (int x = 0; x < 8; ++x) acc[x] = bias[oc];

  const float* wp = w + (long)oc * CIN * 9;
  for (int ic = 0; ic < CIN; ++ic) {
    float wr[9];
#pragma unroll
    for (int q = 0; q < 9; ++q) wr[q] = wp[ic * 9 + q];
    const float* ib = &img[ic * 100 + y * 10];
#pragma unroll
    for (int ky = 0; ky < 3; ++ky) {
      const float* r = ib + ky * 10;
      float c0 = r[0], c1 = r[1];
#pragma unroll
      for (int x = 0; x < 8; ++x) {
        float c2 = r[x + 2];
        acc[x] = fmaf(c0, wr[ky * 3 + 0],
                 fmaf(c1, wr[ky * 3 + 1],
                 fmaf(c2, wr[ky * 3 + 2], acc[x])));
        c0 = c1; c1 = c2;
      }
    }
  }
  float* dst = out + ((long)n * Cout + oc) * 64 + y * 8;
#pragma unroll
  for (int x = 0; x < 8; ++x) dst[x] = fmaxf(acc[x], 0.f);
}

// ---------------- transposed conv as dilated conv3x3 ------------------------
// Equivalence (verified tap-by-tap vs the validated gather form):
//   out[oy][ox] = sum_{ky,kx,ic} D[ic][oy+ky][ox+kx] * w[ic][oc][2-ky][2-kx]
// where D is the input zero-dilated by S with 1 leading pad and (1+OP)
// trailing pad per axis: D[ic][1+iy*S][1+ix*S] = in[ic][iy][ix], else 0.
// DW = (IH-1)*S + 3 + OP.  Thread = (ocLocal, y), acc[OH] over x,
// 9 weights hoisted per ic (contiguous reversed read; broadcast across y).
template <int CIN, int IH, int S, int OP, int OH>
__global__ __launch_bounds__(256) void convT_fast_kernel(
    const float* __restrict__ in, const float* __restrict__ w,
    const float* __restrict__ bias, float* __restrict__ out,
    int Cout, int relu)
{
  constexpr int DW = (IH - 1) * S + 3 + OP;
  constexpr int OCPB = 256 / OH;
  __shared__ float img[CIN * DW * DW];

  const int n = blockIdx.x;
  const int tid = threadIdx.x;
  for (int i = tid; i < CIN * DW * DW; i += 256) img[i] = 0.f;
  __syncthreads();
  const float* src = in + (long)n * CIN * IH * IH;
  for (int i = tid; i < CIN * IH * IH; i += 256) {
    int ic = i / (IH * IH), p = i % (IH * IH);
    int iy = p / IH, ix = p % IH;
    img[ic * DW * DW + (1 + iy * S) * DW + (1 + ix * S)] = src[i];
  }
  __syncthreads();

  const int y  = tid % OH;
  const int oc = blockIdx.y * OCPB + tid / OH;
  if (oc >= Cout) return;

  float acc[OH];
#pragma unroll
  for (int x = 0; x < OH; ++x) acc[x] = bias[oc];

  for (int ic = 0; ic < CIN; ++ic) {
    const float* wp = w + ((long)ic * Cout + oc) * 9;
    float wr[9];
#pragma unroll
    for (int q = 0; q < 9; ++q) wr[q] = wp[8 - q];   // flip(2-ky,2-kx)
    const float* ib = &img[ic * DW * DW + y * DW];
#pragma unroll
    for (int ky = 0; ky < 3; ++ky) {
      const float* r = ib + ky * DW;
      float c0 = r[0], c1 = r[1];
#pragma unroll
      for (int x = 0; x < OH; ++x) {
        float c2 = r[x + 2];
        acc[x] = fmaf(c0, wr[ky * 3 + 0],
                 fmaf(c1, wr[ky * 3 + 1],
                 fmaf(c2, wr[ky * 3 + 2], acc[x])));
        c0 = c1; c1 = c2;
      }
    }
  }
  float* dst = out + ((long)n * Cout + oc) * OH * OH + y * OH;
#pragma unroll
  for (int x = 0; x < OH; ++x) dst[x] = relu ? fmaxf(acc[x], 0.f) : acc[x];
}

// ---------------- LayerNorm (D=512), optional residual add ------------------
__device__ __forceinline__ float blockReduceSum256(float v)
{
  __shared__ float sb[4];
  int lane = threadIdx.x & 63, wid = threadIdx.x >> 6;
#pragma unroll
  for (int o = 32; o; o >>= 1) v += __shfl_down(v, o);
  __syncthreads();
  if (lane == 0) sb[wid] = v;
  __syncthreads();
  return sb[0] + sb[1] + sb[2] + sb[3];
}

__global__ __launch_bounds__(256) void add_ln_kernel(
    const float* __restrict__ a, const float* __restrict__ b,
    const float* __restrict__ w, const float* __restrict__ bb,
    float* __restrict__ out)
{
  long row = blockIdx.x;
  const float* pa = a + row * 512;
  float x0 = pa[threadIdx.x], x1 = pa[threadIdx.x + 256];
  if (b) {
    const float* pb = b + row * 512;
    x0 += pb[threadIdx.x]; x1 += pb[threadIdx.x + 256];
  }
  float mean = blockReduceSum256(x0 + x1) * (1.f / 512.f);
  float d0 = x0 - mean, d1 = x1 - mean;
  float var = blockReduceSum256(d0 * d0 + d1 * d1) * (1.f / 512.f);
  float inv = 1.0f / sqrtf(var + 1e-5f);
  float* po = out + row * 512;
  po[threadIdx.x]       = d0 * inv * w[threadIdx.x] + bb[threadIdx.x];
  po[threadIdx.x + 256] = d1 * inv * w[threadIdx.x + 256] + bb[threadIdx.x + 256];
}

// ---------------- causal softmax over scores [64, T, T] ---------------------
__global__ __launch_bounds__(256) void softmax_kernel(float* __restrict__ sc, float scale)
{
  long row = (long)blockIdx.x * 4 + (threadIdx.x >> 6);
  int lane = threadIdx.x & 63;
  if (row >= (long)64 * TT) return;
  int q = (int)(row % TT);
  float* p = sc + row * TT;
  int len = q + 1;
  float mx = -1e30f;
  for (int j = lane; j < len; j += 64) mx = fmaxf(mx, p[j] * scale);
#pragma unroll
  for (int o = 32; o; o >>= 1) mx = fmaxf(mx, __shfl_xor(mx, o));
  float sum = 0.f;
  for (int j = lane; j < len; j += 64) {
    float e = expf(p[j] * scale - mx);
    p[j] = e;
    sum += e;
  }
#pragma unroll
  for (int o = 32; o; o >>= 1) sum += __shfl_xor(sum, o);
  float inv = 1.0f / sum;
  for (int j = lane; j < TT; j += 64) p[j] = (j < len) ? p[j] * inv : 0.f;
}

// ---------------- small elementwise kernels ---------------------------------
__global__ void lin1_relu_kernel(const float* __restrict__ x, const float* __restrict__ w,
                                 const float* __restrict__ b, float* __restrict__ out, long total)
{
  long idx = (long)blockIdx.x * 256 + threadIdx.x;
  if (idx >= total) return;
  int d = idx & 511; long r = idx >> 9;
  out[idx] = fmaxf(fmaf(x[r], w[d], b[d]), 0.f);
}

__global__ void lin1_relu_int_kernel(const int* __restrict__ x, const float* __restrict__ w,
                                     const float* __restrict__ b, float* __restrict__ out, long total)
{
  long idx = (long)blockIdx.x * 256 + threadIdx.x;
  if (idx >= total) return;
  int d = idx & 511; long r = idx >> 9;
  out[idx] = fmaxf(fmaf((float)x[r], w[d], b[d]), 0.f);
}

__global__ void build_comb_kernel(const float* __restrict__ r, const float* __restrict__ s,
                                  const float* __restrict__ a, const float* __restrict__ t,
                                  float* __restrict__ comb)
{
  long idx = (long)blockIdx.x * 256 + threadIdx.x;
  if (idx >= (long)8 * TT * 512) return;
  int d = idx & 511;
  long rr = idx >> 9;
  int tok = (int)(rr % TT);
  int b   = (int)(rr / TT);
  int grp = tok / 3, ph = tok % 3;
  float te = t[((long)b * 128 + grp) * 512 + d];
  float v;
  if (ph == 0)      v = r[((long)b * 128 + grp) * 512 + d] + te;
  else if (ph == 1) v = s[((long)b * 128 + grp) * 512 + d] + te;
  else              v = a[((long)b * 127 + grp) * 512 + d] + te;
  comb[idx] = v;
}

__global__ void gather3_kernel(const float* __restrict__ x, float* __restrict__ out,
                               int offset, int count)
{
  long idx = (long)blockIdx.x * 256 + threadIdx.x;
  long total = (long)8 * count * 512;
  if (idx >= total) return;
  int d = idx & 511;
  long r = idx >> 9;
  int i = (int)(r % count);
  int b = (int)(r / count);
  out[idx] = x[((long)b * TT + offset + 3 * i) * 512 + d];
}

__global__ __launch_bounds__(256) void reward_kernel(const float* __restrict__ x,
                                                     const float* __restrict__ w,
                                                     const float* __restrict__ b,
                                                     float* __restrict__ out, int rows)
{
  int row = blockIdx.x * 4 + (threadIdx.x >> 6);
  int lane = threadIdx.x & 63;
  if (row >= rows) return;
  const float* p = x + (long)row * 512;
  float s = 0.f;
  for (int j = lane; j < 512; j += 64) s = fmaf(p[j], w[j], s);
#pragma unroll
  for (int o = 32; o; o >>= 1) s += __shfl_xor(s, o);
  if (lane == 0) out[row] = s + b[0];
}

// ---------------------------------------------------------------------------
extern "C" void kernel_launch(void* const* d_in, const int* in_sizes, int n_in,
                              void* d_out, int out_size, void* d_ws, size_t ws_size,
                              hipStream_t stream)
{
  const float* states  = (const float*)d_in[0];
  const float* rtgs    = (const float*)d_in[1];
  const int*   tsteps  = (const int*)d_in[2];
  const float* actions = (const float*)d_in[3];
  // d_in[4] mask: tril, hardcoded causal
  const float* se_c1w = (const float*)d_in[5];  const float* se_c1b = (const float*)d_in[6];
  const float* se_c2w = (const float*)d_in[7];  const float* se_c2b = (const float*)d_in[8];
  const float* se_c3w = (const float*)d_in[9];  const float* se_c3b = (const float*)d_in[10];
  const float* se_fcw = (const float*)d_in[11]; const float* se_fcb = (const float*)d_in[12];
  const float* se_lnw = (const float*)d_in[13]; const float* se_lnb = (const float*)d_in[14];
  const float* ae_c1w = (const float*)d_in[15]; const float* ae_c1b = (const float*)d_in[16];
  const float* ae_c2w = (const float*)d_in[17]; const float* ae_c2b = (const float*)d_in[18];
  const float* ae_c3w = (const float*)d_in[19]; const float* ae_c3b = (const float*)d_in[20];
  const float* ae_fcw = (const float*)d_in[21]; const float* ae_fcb = (const float*)d_in[22];
  const float* ae_lnw = (const float*)d_in[23]; const float* ae_lnb = (const float*)d_in[24];
  const float* rtg_w1 = (const float*)d_in[25]; const float* rtg_b1 = (const float*)d_in[26];
  const float* rtg_w2 = (const float*)d_in[27]; const float* rtg_b2 = (const float*)d_in[28];
  const float* rtg_lnw= (const float*)d_in[29]; const float* rtg_lnb= (const float*)d_in[30];
  const float* ts_w1  = (const float*)d_in[31]; const float* ts_b1  = (const float*)d_in[32];
  const float* ts_w2  = (const float*)d_in[33]; const float* ts_b2  = (const float*)d_in[34];
  const float* ts_lnw = (const float*)d_in[35]; const float* ts_lnb = (const float*)d_in[36];
  const float* ip_w   = (const float*)d_in[37]; const float* ip_b   = (const float*)d_in[38];
  const float* lyr_wq = (const float*)d_in[39]; const float* lyr_bq = (const float*)d_in[40];
  const float* lyr_wk = (const float*)d_in[41]; const float* lyr_bk = (const float*)d_in[42];
  const float* lyr_wv = (const float*)d_in[43]; const float* lyr_bv = (const float*)d_in[44];
  const float* lyr_wo = (const float*)d_in[45]; const float* lyr_bo = (const float*)d_in[46];
  const float* lyr_f1w= (const float*)d_in[47]; const float* lyr_f1b= (const float*)d_in[48];
  const float* lyr_f2w= (const float*)d_in[49]; const float* lyr_f2b= (const float*)d_in[50];
  const float* lyr_l1w= (const float*)d_in[51]; const float* lyr_l1b= (const float*)d_in[52];
  const float* lyr_l2w= (const float*)d_in[53]; const float* lyr_l2b= (const float*)d_in[54];
  const float* ad_fcw = (const float*)d_in[55]; const float* ad_fcb = (const float*)d_in[56];
  const float* ad_w1  = (const float*)d_in[57]; const float* ad_b1  = (const float*)d_in[58];
  const float* ad_w2  = (const float*)d_in[59]; const float* ad_b2  = (const float*)d_in[60];
  const float* ad_w3  = (const float*)d_in[61]; const float* ad_b3  = (const float*)d_in[62];
  const float* sd_fcw = (const float*)d_in[63]; const float* sd_fcb = (const float*)d_in[64];
  const float* sd_w1  = (const float*)d_in[65]; const float* sd_b1  = (const float*)d_in[66];
  const float* sd_w2  = (const float*)d_in[67]; const float* sd_b2  = (const float*)d_in[68];
  const float* sd_w3  = (const float*)d_in[69]; const float* sd_b3  = (const float*)d_in[70];
  const float* rp_w   = (const float*)d_in[71]; const float* rp_b   = (const float*)d_in[72];

  float* ws = (float*)d_ws;
  long off = 0;
  auto alloc = [&](long n) { float* p = ws + off; off += n; return p; };

  float* region = alloc(10485760);          // conv bufs / scores / decoder bufs
  float* h1 = region;                        // 1024*32*64
  float* h2 = region + 2097152;              // 1024*64*64
  float* h3 = region + 6291456;              // 1024*64*64
  float* scores = region;                    // 64*383*383 = 9,388,096
  float* s_emb = alloc(524288);
  float* a_emb = alloc(520192);
  float* r_emb = alloc(524288);
  float* t_emb = alloc(524288);
  float* etmp  = alloc(524288);
  float* xa = alloc(1568768);
  float* xb = alloc(1568768);
  float* qb = alloc(1568768);
  float* kb = alloc(1568768);
  float* vb = alloc(1568768);
  float* ao = alloc(1568768);
  float* t2 = alloc(1568768);
  float* ffh = alloc(6275072);

  // bf16 region (ushort) after the float region
  unsigned short* bws = (unsigned short*)(ws + off);
  long boff = 0;
  auto ballo = [&](long n) { unsigned short* p = bws + boff; boff += n; return p; };
  unsigned short* ipW  = ballo(262144);
  unsigned short* wqW  = ballo(6L * 262144);
  unsigned short* wkW  = ballo(6L * 262144);
  unsigned short* wvW  = ballo(6L * 262144);
  unsigned short* woW  = ballo(6L * 262144);
  unsigned short* f1W  = ballo(6L * 1048576);
  unsigned short* f2W  = ballo(6L * 1048576);
  unsigned short* seW  = ballo(2097152);
  unsigned short* aeW  = ballo(2097152);
  unsigned short* rtgW = ballo(262144);
  unsigned short* tsW  = ballo(262144);
  unsigned short* adW  = ballo(262144);
  unsigned short* sdW  = ballo(262144);
  unsigned short* abuf = ballo(6275072);     // activation cast scratch

  const long T2 = (long)TT * TT;             // 146689
  const long BT = (long)8 * TT;              // 3064

  // ---------------- weight pre-casts (fp32 -> bf16) ----------------
  cast_bf(stream, ip_w,    ipW,  262144);
  cast_bf(stream, lyr_wq,  wqW,  6L * 262144);
  cast_bf(stream, lyr_wk,  wkW,  6L * 262144);
  cast_bf(stream, lyr_wv,  wvW,  6L * 262144);
  cast_bf(stream, lyr_wo,  woW,  6L * 262144);
  cast_bf(stream, lyr_f1w, f1W,  6L * 1048576);
  cast_bf(stream, lyr_f2w, f2W,  6L * 1048576);
  cast_bf(stream, se_fcw,  seW,  2097152);
  cast_bf(stream, ae_fcw,  aeW,  2097152);
  cast_bf(stream, rtg_w2,  rtgW, 262144);
  cast_bf(stream, ts_w2,   tsW,  262144);
  cast_bf(stream, ad_fcw,  adW,  262144);
  cast_bf(stream, sd_fcw,  sdW,  262144);

  // ---------------- encoders ----------------
  // state CNN (1024 images)
  conv3x3_kernel<14><<<dim3(1024, 1), 256, 0, stream>>>(states, se_c1w, se_c1b, h1, 32);
  conv3x3_kernel<32><<<dim3(1024, 2), 256, 0, stream>>>(h1, se_c2w, se_c2b, h2, 64);
  conv3x3_kernel<64><<<dim3(1024, 2), 256, 0, stream>>>(h2, se_c3w, se_c3b, h3, 64);
  cast_bf(stream, h3, abuf, 1024L * 4096);
  gemm_bf(stream, abuf, seW, se_fcb, etmp, 1024, 512, 4096);
  add_ln_kernel<<<1024, 256, 0, stream>>>(etmp, nullptr, se_lnw, se_lnb, s_emb);

  // action CNN (1016 images)
  conv3x3_kernel<73><<<dim3(1016, 1), 256, 0, stream>>>(actions, ae_c1w, ae_c1b, h1, 32);
  conv3x3_kernel<32><<<dim3(1016, 2), 256, 0, stream>>>(h1, ae_c2w, ae_c2b, h2, 64);
  conv3x3_kernel<64><<<dim3(1016, 2), 256, 0, stream>>>(h2, ae_c3w, ae_c3b, h3, 64);
  cast_bf(stream, h3, abuf, 1016L * 4096);
  gemm_bf(stream, abuf, aeW, ae_fcb, etmp, 1016, 512, 4096);
  add_ln_kernel<<<1016, 256, 0, stream>>>(etmp, nullptr, ae_lnw, ae_lnb, a_emb);

  // rtg MLP (1024 rows)
  lin1_relu_kernel<<<(1024 * 512 + 255) / 256, 256, 0, stream>>>(rtgs, rtg_w1, rtg_b1, qb, 1024 * 512);
  cast_bf(stream, qb, abuf, 1024L * 512);
  gemm_bf(stream, abuf, rtgW, rtg_b2, etmp, 1024, 512, 512);
  add_ln_kernel<<<1024, 256, 0, stream>>>(etmp, nullptr, rtg_lnw, rtg_lnb, r_emb);

  // timestep MLP (1024 rows)
  lin1_relu_int_kernel<<<(1024 * 512 + 255) / 256, 256, 0, stream>>>(tsteps, ts_w1, ts_b1, qb, 1024 * 512);
  cast_bf(stream, qb, abuf, 1024L * 512);
  gemm_bf(stream, abuf, tsW, ts_b2, etmp, 1024, 512, 512);
  add_ln_kernel<<<1024, 256, 0, stream>>>(etmp, nullptr, ts_lnw, ts_lnb, t_emb);

  // interleave + input projection
  build_comb_kernel<<<(int)((8L * TT * 512 + 255) / 256), 256, 0, stream>>>(r_emb, s_emb, a_emb, t_emb, xb);
  cast_bf(stream, xb, abuf, BT * 512);
  gemm_bf(stream, abuf, ipW, ip_b, xa, (int)BT, 512, 512);

  // ---------------- transformer layers ----------------
  for (int l = 0; l < 6; ++l) {
    const unsigned short* wq = wqW + (long)l * 262144; const float* bq = lyr_bq + (long)l * 512;
    const unsigned short* wk = wkW + (long)l * 262144; const float* bk = lyr_bk + (long)l * 512;
    const unsigned short* wv = wvW + (long)l * 262144; const float* bv = lyr_bv + (long)l * 512;
    const unsigned short* wo = woW + (long)l * 262144; const float* bo = lyr_bo + (long)l * 512;
    const unsigned short* f1w = f1W + (long)l * 1048576; const float* f1b = lyr_f1b + (long)l * 2048;
    const unsigned short* f2w = f2W + (long)l * 1048576; const float* f2b = lyr_f2b + (long)l * 512;
    const float* l1w = lyr_l1w + (long)l * 512; const float* l1b = lyr_l1b + (long)l * 512;
    const float* l2w = lyr_l2w + (long)l * 512; const float* l2b = lyr_l2b + (long)l * 512;

    cast_bf(stream, xa, abuf, BT * 512);
    gemm_bf(stream, abuf, wq, bq, qb, (int)BT, 512, 512);
    gemm_bf(stream, abuf, wk, bk, kb, (int)BT, 512, 512);
    gemm_bf(stream, abuf, wv, bv, vb, (int)BT, 512, 512);

    // scores[b,h] = Q[b,:,h*64:] @ K[b,:,h*64:]^T   (M=N=383, K=64)  [fp32]
    gemm(stream, qb, kb, nullptr, scores, TT, TT, 64, 512, 512, TT,
         (long)TT * 512, 64, (long)TT * 512, 64, 8 * T2, T2, 8, 64, 1, 0);
    softmax_kernel<<<6128, 256, 0, stream>>>(scores, 0.125f);
    // attout[b,:,h*64:] = P[b,h] @ V[b,:,h*64:]     (M=383, N=64, K=383) [fp32]
    gemm(stream, scores, vb, nullptr, ao, TT, 64, TT, TT, 512, 512,
         8 * T2, T2, (long)TT * 512, 64, (long)TT * 512, 64, 8, 64, 0, 0);

    cast_bf(stream, ao, abuf, BT * 512);
    gemm_bf(stream, abuf, wo, bo, t2, (int)BT, 512, 512);
    add_ln_kernel<<<(int)BT, 256, 0, stream>>>(xa, t2, l1w, l1b, xb);
    cast_bf(stream, xb, abuf, BT * 512);
    gemm_bf(stream, abuf, f1w, f1b, ffh, (int)BT, 2048, 512, 1);   // relu
    cast_bf(stream, ffh, abuf, BT * 2048);
    gemm_bf(stream, abuf, f2w, f2b, t2, (int)BT, 512, 2048);
    add_ln_kernel<<<(int)BT, 256, 0, stream>>>(xb, t2, l2w, l2b, xa);
  }

  // ---------------- decoders ----------------
  float* outp = (float*)d_out;
  float* act_out = outp;              // 8*128*73*64 = 4,784,128
  float* st_out  = outp + 4784128;    // 8*128*14*64 = 917,504
  float* rw_out  = outp + 5701632;    // 8*127 = 1016

  float* za  = region;                // 524288
  float* zfc = region + 524288;       // 524288
  float* dh1 = region + 1048576;      // 1024*64*16
  float* dh2 = region + 2097152;      // 1024*32*64

  // action decoder reads x[:,1::3]
  gather3_kernel<<<(1024 * 512 + 255) / 256, 256, 0, stream>>>(xa, za, 1, 128);
  cast_bf(stream, za, abuf, 1024L * 512);
  gemm_bf(stream, abuf, adW, ad_fcb, zfc, 1024, 512, 512, 1);      // relu
  convT_fast_kernel<128, 2, 2, 1, 4><<<dim3(1024, 1), 256, 0, stream>>>(zfc, ad_w1, ad_b1, dh1, 64, 1);
  convT_fast_kernel<64, 4, 2, 1, 8><<<dim3(1024, 1), 256, 0, stream>>>(dh1, ad_w2, ad_b2, dh2, 32, 1);
  convT_fast_kernel<32, 8, 1, 0, 8><<<dim3(1024, 3), 256, 0, stream>>>(dh2, ad_w3, ad_b3, act_out, 73, 0);

  // state decoder reads x[:,0::3]
  gather3_kernel<<<(1024 * 512 + 255) / 256, 256, 0, stream>>>(xa, za, 0, 128);
  cast_bf(stream, za, abuf, 1024L * 512);
  gemm_bf(stream, abuf, sdW, sd_fcb, zfc, 1024, 512, 512, 1);      // relu
  convT_fast_kernel<128, 2, 2, 1, 4><<<dim3(1024, 1), 256, 0, stream>>>(zfc, sd_w1, sd_b1, dh1, 64, 1);
  convT_fast_kernel<64, 4, 2, 1, 8><<<dim3(1024, 1), 256, 0, stream>>>(dh1, sd_w2, sd_b2, dh2, 32, 1);
  convT_fast_kernel<32, 8, 1, 0, 8><<<dim3(1024, 1), 256, 0, stream>>>(dh2, sd_w3, sd_b3, st_out, 14, 0);

  // reward head reads x[:,2::3] (127 tokens)
  gather3_kernel<<<(1016 * 512 + 255) / 256, 256, 0, stream>>>(xa, za, 2, 127);
  reward_kernel<<<(1016 + 3) / 4, 256, 0, stream>>>(za, rp_w, rp_b, rw_out, 1016);
}

// Round 6
// 2435.070 us; speedup vs baseline: 1.6999x; 1.3373x over previous
//
#include <hip/hip_runtime.h>

// ---------------------------------------------------------------------------
// Decision-Transformer-like model. bf16-MFMA GEMMs + fused flash attention.
// B=8, L=128, D=512, H=8, DK=64, DFF=2048, NL=6, T=383, SC=14, AC=73
// Round 6: QK^T+softmax+PV fused into one bf16-MFMA flash kernel (was 3 fp32
//          kernels, ~1.4ms, 37.5MB scores traffic/layer). QKV emit bf16.
// ---------------------------------------------------------------------------

#define TT 383

typedef short      bf16x8 __attribute__((ext_vector_type(8)));
typedef float      f32x4  __attribute__((ext_vector_type(4)));
typedef unsigned short u16x8 __attribute__((ext_vector_type(8)));
typedef unsigned short u16x4 __attribute__((ext_vector_type(4)));

// ---------------- fp32 -> bf16 cast (RNE) -----------------------------------
__device__ __forceinline__ unsigned short f2bf(float f)
{
  unsigned u = __float_as_uint(f);
  return (unsigned short)((u + 0x7FFFu + ((u >> 16) & 1u)) >> 16);
}

__global__ __launch_bounds__(256) void cast_bf16_kernel(
    const float* __restrict__ in, unsigned short* __restrict__ out, long n)
{
  long i = ((long)blockIdx.x * 256 + threadIdx.x) * 4;
  if (i >= n) return;
  const float4 v = *(const float4*)(in + i);
  u16x4 o;
  o.x = f2bf(v.x); o.y = f2bf(v.y); o.z = f2bf(v.z); o.w = f2bf(v.w);
  *(u16x4*)(out + i) = o;
}

// ---------------- bf16 MFMA GEMM: C = A @ B^T + bias, relu / bf16-out -------
// A: [M,K] bf16 row-major. B: [N,K] bf16 row-major (weights).
// C: [M,N] fp32, or bf16 when obf=1. K%64==0, N%128==0, M arbitrary.
#define LDAP 72   // padded LDS row (shorts): 144 B
__global__ __launch_bounds__(256) void gemm_bf16_kernel(
    const unsigned short* __restrict__ A, const unsigned short* __restrict__ B,
    const float* __restrict__ bias, float* __restrict__ C,
    int M, int N, int K, int relu, int obf)
{
  __shared__ __align__(16) unsigned short As[128 * LDAP];
  __shared__ __align__(16) unsigned short Bs[128 * LDAP];

  const int tid = threadIdx.x;
  const int lane = tid & 63;
  const int w  = tid >> 6;
  const int wr = w >> 1, wc = w & 1;
  const int m0 = blockIdx.x * 128, n0 = blockIdx.y * 128;

  const int lr = lane & 15;
  const int hi = lane >> 4;

  f32x4 acc[4][4] = {};

  const int r = tid >> 1;
  const int h = tid & 1;

  int mrow = m0 + r; if (mrow >= M) mrow = M - 1;
  const unsigned short* Ap = A + (long)mrow * K + h * 32;
  const unsigned short* Bp = B + (long)(n0 + r) * K + h * 32;
  unsigned short* Asd = As + r * LDAP + h * 32;
  unsigned short* Bsd = Bs + r * LDAP + h * 32;

  for (int k0 = 0; k0 < K; k0 += 64) {
#pragma unroll
    for (int i = 0; i < 4; ++i)
      *(u16x8*)(Asd + i * 8) = *(const u16x8*)(Ap + k0 + i * 8);
#pragma unroll
    for (int i = 0; i < 4; ++i)
      *(u16x8*)(Bsd + i * 8) = *(const u16x8*)(Bp + k0 + i * 8);
    __syncthreads();

#pragma unroll
    for (int kk = 0; kk < 2; ++kk) {
      const int kof = kk * 32 + hi * 8;
      bf16x8 a[4], b[4];
#pragma unroll
      for (int t = 0; t < 4; ++t)
        a[t] = *(const bf16x8*)(As + (wr * 64 + t * 16 + lr) * LDAP + kof);
#pragma unroll
      for (int t = 0; t < 4; ++t)
        b[t] = *(const bf16x8*)(Bs + (wc * 64 + t * 16 + lr) * LDAP + kof);
#pragma unroll
      for (int i = 0; i < 4; ++i)
#pragma unroll
        for (int j = 0; j < 4; ++j)
          acc[i][j] = __builtin_amdgcn_mfma_f32_16x16x32_bf16(a[i], b[j], acc[i][j], 0, 0, 0);
    }
    __syncthreads();
  }

  // C/D layout (HW-verified m89): col = lane&15, row = (lane>>4)*4 + reg
#pragma unroll
  for (int j = 0; j < 4; ++j) {
    const int col = n0 + wc * 64 + j * 16 + lr;
    const float bv = bias ? bias[col] : 0.f;
#pragma unroll
    for (int i = 0; i < 4; ++i) {
#pragma unroll
      for (int v = 0; v < 4; ++v) {
        int row = m0 + wr * 64 + i * 16 + hi * 4 + v;
        if (row < M) {
          float x = acc[i][j][v] + bv;
          if (relu) x = fmaxf(x, 0.f);
          if (obf) ((unsigned short*)C)[(long)row * N + col] = f2bf(x);
          else     C[(long)row * N + col] = x;
        }
      }
    }
  }
}

static inline void gemm_bf(hipStream_t st, const unsigned short* A, const unsigned short* B,
                           const float* bias, float* C, int M, int N, int K,
                           int relu = 0, int obf = 0)
{
  dim3 g((M + 127) / 128, N / 128);
  gemm_bf16_kernel<<<g, 256, 0, st>>>(A, B, bias, C, M, N, K, relu, obf);
}

static inline void cast_bf(hipStream_t st, const float* in, unsigned short* out, long n)
{
  cast_bf16_kernel<<<(int)((n / 4 + 255) / 256), 256, 0, st>>>(in, out, n);
}

// ---------------- fused causal flash attention ------------------------------
// Q,K,V,O: bf16 [B*383][512], head h at cols h*64..h*64+63. scale=0.125.
// Grid (6 q-tiles, 64 bh). 4 waves; wave w owns q-rows [q0+16w, q0+16w+16).
// KV steps of 32. S row (q) = hi*4+reg, col (kv) = lane&15 (C layout, m89).
__global__ __launch_bounds__(256) void attn_kernel(
    const unsigned short* __restrict__ Qb, const unsigned short* __restrict__ Kb,
    const unsigned short* __restrict__ Vb, unsigned short* __restrict__ Ob)
{
  __shared__ __align__(16) unsigned short Kl[32 * 72];
  __shared__ __align__(16) unsigned short Vt[64 * 40];     // V transposed [d][kv]
  __shared__ __align__(16) unsigned short Pl[4][16 * 40];  // per-wave P

  const int tid = threadIdx.x;
  const int lane = tid & 63;
  const int w = tid >> 6;
  const int lr = lane & 15, hi = lane >> 4;
  const int q0 = blockIdx.x * 64;
  const int bh = blockIdx.y;
  const int b = bh >> 3, h = bh & 7;
  const long base = (long)b * TT * 512 + h * 64;

  const int qrow = q0 + w * 16 + lr;
  const int qr_c = qrow < TT ? qrow : TT - 1;
  bf16x8 qf0 = *(const bf16x8*)(Qb + base + (long)qr_c * 512 + hi * 8);
  bf16x8 qf1 = *(const bf16x8*)(Qb + base + (long)qr_c * 512 + 32 + hi * 8);

  float m[4], l[4];
  f32x4 acc[4];
#pragma unroll
  for (int r = 0; r < 4; ++r) { m[r] = -1e30f; l[r] = 0.f; }
#pragma unroll
  for (int c = 0; c < 4; ++c) acc[c] = (f32x4){0.f, 0.f, 0.f, 0.f};

  const int qmax = min(q0 + 63, TT - 1);
  const int nkv = qmax + 1;

  for (int kv0 = 0; kv0 < nkv; kv0 += 32) {
    __syncthreads();
    {   // stage K rows + V transposed (bf16 copies), 8 elems/thread each
      int e = tid * 8;
      int kv = e >> 6, d = e & 63;
      int skv = kv0 + kv; if (skv >= TT) skv = TT - 1;    // masked below
      *(u16x8*)(Kl + kv * 72 + d) = *(const u16x8*)(Kb + base + (long)skv * 512 + d);
      u16x8 vv = *(const u16x8*)(Vb + base + (long)skv * 512 + d);
#pragma unroll
      for (int j = 0; j < 8; ++j) Vt[(d + j) * 40 + kv] = vv[j];
    }
    __syncthreads();

    f32x4 s[2] = {};
#pragma unroll
    for (int t = 0; t < 2; ++t) {
      bf16x8 k0 = *(const bf16x8*)(Kl + (t * 16 + lr) * 72 + hi * 8);
      bf16x8 k1 = *(const bf16x8*)(Kl + (t * 16 + lr) * 72 + 32 + hi * 8);
      s[t] = __builtin_amdgcn_mfma_f32_16x16x32_bf16(qf0, k0, s[t], 0, 0, 0);
      s[t] = __builtin_amdgcn_mfma_f32_16x16x32_bf16(qf1, k1, s[t], 0, 0, 0);
    }

    const int qq = q0 + w * 16 + hi * 4;
#pragma unroll
    for (int r = 0; r < 4; ++r) {
      float v0 = s[0][r] * 0.125f;
      float v1 = s[1][r] * 0.125f;
      const int qr = qq + r;
      const int kvA = kv0 + lr, kvB = kv0 + 16 + lr;
      if (kvA > qr || kvA >= TT) v0 = -1e30f;
      if (kvB > qr || kvB >= TT) v1 = -1e30f;
      float rm = fmaxf(v0, v1);
      rm = fmaxf(rm, __shfl_xor(rm, 1));
      rm = fmaxf(rm, __shfl_xor(rm, 2));
      rm = fmaxf(rm, __shfl_xor(rm, 4));
      rm = fmaxf(rm, __shfl_xor(rm, 8));
      float mn = fmaxf(m[r], rm);
      float al = expf(m[r] - mn);
      float e0 = expf(v0 - mn);
      float e1 = expf(v1 - mn);
      float rs = e0 + e1;
      rs += __shfl_xor(rs, 1);
      rs += __shfl_xor(rs, 2);
      rs += __shfl_xor(rs, 4);
      rs += __shfl_xor(rs, 8);
      l[r] = l[r] * al + rs;
      m[r] = mn;
#pragma unroll
      for (int c = 0; c < 4; ++c) acc[c][r] *= al;
      Pl[w][(hi * 4 + r) * 40 + lr]      = f2bf(e0);
      Pl[w][(hi * 4 + r) * 40 + 16 + lr] = f2bf(e1);
    }

    // O += P(16x32) . V(32x64)
    bf16x8 pa = *(const bf16x8*)(&Pl[w][lr * 40 + hi * 8]);
#pragma unroll
    for (int c = 0; c < 4; ++c) {
      bf16x8 vf = *(const bf16x8*)(Vt + (c * 16 + lr) * 40 + hi * 8);
      acc[c] = __builtin_amdgcn_mfma_f32_16x16x32_bf16(pa, vf, acc[c], 0, 0, 0);
    }
  }

  float inv[4];
#pragma unroll
  for (int r = 0; r < 4; ++r) inv[r] = 1.0f / l[r];
#pragma unroll
  for (int c = 0; c < 4; ++c) {
#pragma unroll
    for (int r = 0; r < 4; ++r) {
      int qr = q0 + w * 16 + hi * 4 + r;
      if (qr < TT) Ob[base + (long)qr * 512 + c * 16 + lr] = f2bf(acc[c][r] * inv[r]);
    }
  }
}

// ---------------- direct 3x3 conv (pad 1, 8x8, relu) ------------------------
template <int CIN>
__global__ __launch_bounds__(256) void conv3x3_kernel(
    const float* __restrict__ in, const float* __restrict__ w,
    const float* __restrict__ bias, float* __restrict__ out, int Cout)
{
  __shared__ float img[CIN * 100];
  const int n = blockIdx.x;
  const int tid = threadIdx.x;
  for (int i = tid; i < CIN * 100; i += 256) img[i] = 0.f;
  __syncthreads();
  const float* src = in + (long)n * CIN * 64;
  for (int i = tid; i < CIN * 64; i += 256) {
    int ic = i >> 6, p = i & 63;
    img[ic * 100 + ((p >> 3) + 1) * 10 + (p & 7) + 1] = src[i];
  }
  __syncthreads();

  const int y  = tid & 7;
  const int oc = blockIdx.y * 32 + (tid >> 3);
  if (oc >= Cout) return;

  float acc[8];
#pragma unroll
  for (int x = 0; x < 8; ++x) acc[x] = bias[oc];

  const float* wp = w + (long)oc * CIN * 9;
  for (int ic = 0; ic < CIN; ++ic) {
    float wr[9];
#pragma unroll
    for (int q = 0; q < 9; ++q) wr[q] = wp[ic * 9 + q];
    const float* ib = &img[ic * 100 + y * 10];
#pragma unroll
    for (int ky = 0; ky < 3; ++ky) {
      const float* r = ib + ky * 10;
      float c0 = r[0], c1 = r[1];
#pragma unroll
      for (int x = 0; x < 8; ++x) {
        float c2 = r[x + 2];
        acc[x] = fmaf(c0, wr[ky * 3 + 0],
                 fmaf(c1, wr[ky * 3 + 1],
                 fmaf(c2, wr[ky * 3 + 2], acc[x])));
        c0 = c1; c1 = c2;
      }
    }
  }
  float* dst = out + ((long)n * Cout + oc) * 64 + y * 8;
#pragma unroll
  for (int x = 0; x < 8; ++x) dst[x] = fmaxf(acc[x], 0.f);
}

// ---------------- transposed conv as dilated conv3x3 ------------------------
template <int CIN, int IH, int S, int OP, int OH>
__global__ __launch_bounds__(256) void convT_fast_kernel(
    const float* __restrict__ in, const float* __restrict__ w,
    const float* __restrict__ bias, float* __restrict__ out,
    int Cout, int relu)
{
  constexpr int DW = (IH - 1) * S + 3 + OP;
  constexpr int OCPB = 256 / OH;
  __shared__ float img[CIN * DW * DW];

  const int n = blockIdx.x;
  const int tid = threadIdx.x;
  for (int i = tid; i < CIN * DW * DW; i += 256) img[i] = 0.f;
  __syncthreads();
  const float* src = in + (long)n * CIN * IH * IH;
  for (int i = tid; i < CIN * IH * IH; i += 256) {
    int ic = i / (IH * IH), p = i % (IH * IH);
    int iy = p / IH, ix = p % IH;
    img[ic * DW * DW + (1 + iy * S) * DW + (1 + ix * S)] = src[i];
  }
  __syncthreads();

  const int y  = tid % OH;
  const int oc = blockIdx.y * OCPB + tid / OH;
  if (oc >= Cout) return;

  float acc[OH];
#pragma unroll
  for (int x = 0; x < OH; ++x) acc[x] = bias[oc];

  for (int ic = 0; ic < CIN; ++ic) {
    const float* wp = w + ((long)ic * Cout + oc) * 9;
    float wr[9];
#pragma unroll
    for (int q = 0; q < 9; ++q) wr[q] = wp[8 - q];
    const float* ib = &img[ic * DW * DW + y * DW];
#pragma unroll
    for (int ky = 0; ky < 3; ++ky) {
      const float* r = ib + ky * DW;
      float c0 = r[0], c1 = r[1];
#pragma unroll
      for (int x = 0; x < OH; ++x) {
        float c2 = r[x + 2];
        acc[x] = fmaf(c0, wr[ky * 3 + 0],
                 fmaf(c1, wr[ky * 3 + 1],
                 fmaf(c2, wr[ky * 3 + 2], acc[x])));
        c0 = c1; c1 = c2;
      }
    }
  }
  float* dst = out + ((long)n * Cout + oc) * OH * OH + y * OH;
#pragma unroll
  for (int x = 0; x < OH; ++x) dst[x] = relu ? fmaxf(acc[x], 0.f) : acc[x];
}

// ---------------- LayerNorm (D=512), optional residual add ------------------
__device__ __forceinline__ float blockReduceSum256(float v)
{
  __shared__ float sb[4];
  int lane = threadIdx.x & 63, wid = threadIdx.x >> 6;
#pragma unroll
  for (int o = 32; o; o >>= 1) v += __shfl_down(v, o);
  __syncthreads();
  if (lane == 0) sb[wid] = v;
  __syncthreads();
  return sb[0] + sb[1] + sb[2] + sb[3];
}

__global__ __launch_bounds__(256) void add_ln_kernel(
    const float* __restrict__ a, const float* __restrict__ b,
    const float* __restrict__ w, const float* __restrict__ bb,
    float* __restrict__ out)
{
  long row = blockIdx.x;
  const float* pa = a + row * 512;
  float x0 = pa[threadIdx.x], x1 = pa[threadIdx.x + 256];
  if (b) {
    const float* pb = b + row * 512;
    x0 += pb[threadIdx.x]; x1 += pb[threadIdx.x + 256];
  }
  float mean = blockReduceSum256(x0 + x1) * (1.f / 512.f);
  float d0 = x0 - mean, d1 = x1 - mean;
  float var = blockReduceSum256(d0 * d0 + d1 * d1) * (1.f / 512.f);
  float inv = 1.0f / sqrtf(var + 1e-5f);
  float* po = out + row * 512;
  po[threadIdx.x]       = d0 * inv * w[threadIdx.x] + bb[threadIdx.x];
  po[threadIdx.x + 256] = d1 * inv * w[threadIdx.x + 256] + bb[threadIdx.x + 256];
}

// ---------------- small elementwise kernels ---------------------------------
__global__ void lin1_relu_kernel(const float* __restrict__ x, const float* __restrict__ w,
                                 const float* __restrict__ b, float* __restrict__ out, long total)
{
  long idx = (long)blockIdx.x * 256 + threadIdx.x;
  if (idx >= total) return;
  int d = idx & 511; long r = idx >> 9;
  out[idx] = fmaxf(fmaf(x[r], w[d], b[d]), 0.f);
}

__global__ void lin1_relu_int_kernel(const int* __restrict__ x, const float* __restrict__ w,
                                     const float* __restrict__ b, float* __restrict__ out, long total)
{
  long idx = (long)blockIdx.x * 256 + threadIdx.x;
  if (idx >= total) return;
  int d = idx & 511; long r = idx >> 9;
  out[idx] = fmaxf(fmaf((float)x[r], w[d], b[d]), 0.f);
}

__global__ void build_comb_kernel(const float* __restrict__ r, const float* __restrict__ s,
                                  const float* __restrict__ a, const float* __restrict__ t,
                                  float* __restrict__ comb)
{
  long idx = (long)blockIdx.x * 256 + threadIdx.x;
  if (idx >= (long)8 * TT * 512) return;
  int d = idx & 511;
  long rr = idx >> 9;
  int tok = (int)(rr % TT);
  int b   = (int)(rr / TT);
  int grp = tok / 3, ph = tok % 3;
  float te = t[((long)b * 128 + grp) * 512 + d];
  float v;
  if (ph == 0)      v = r[((long)b * 128 + grp) * 512 + d] + te;
  else if (ph == 1) v = s[((long)b * 128 + grp) * 512 + d] + te;
  else              v = a[((long)b * 127 + grp) * 512 + d] + te;
  comb[idx] = v;
}

__global__ void gather3_kernel(const float* __restrict__ x, float* __restrict__ out,
                               int offset, int count)
{
  long idx = (long)blockIdx.x * 256 + threadIdx.x;
  long total = (long)8 * count * 512;
  if (idx >= total) return;
  int d = idx & 511;
  long r = idx >> 9;
  int i = (int)(r % count);
  int b = (int)(r / count);
  out[idx] = x[((long)b * TT + offset + 3 * i) * 512 + d];
}

__global__ __launch_bounds__(256) void reward_kernel(const float* __restrict__ x,
                                                     const float* __restrict__ w,
                                                     const float* __restrict__ b,
                                                     float* __restrict__ out, int rows)
{
  int row = blockIdx.x * 4 + (threadIdx.x >> 6);
  int lane = threadIdx.x & 63;
  if (row >= rows) return;
  const float* p = x + (long)row * 512;
  float s = 0.f;
  for (int j = lane; j < 512; j += 64) s = fmaf(p[j], w[j], s);
#pragma unroll
  for (int o = 32; o; o >>= 1) s += __shfl_xor(s, o);
  if (lane == 0) out[row] = s + b[0];
}

// ---------------------------------------------------------------------------
extern "C" void kernel_launch(void* const* d_in, const int* in_sizes, int n_in,
                              void* d_out, int out_size, void* d_ws, size_t ws_size,
                              hipStream_t stream)
{
  const float* states  = (const float*)d_in[0];
  const float* rtgs    = (const float*)d_in[1];
  const int*   tsteps  = (const int*)d_in[2];
  const float* actions = (const float*)d_in[3];
  // d_in[4] mask: tril, hardcoded causal
  const float* se_c1w = (const float*)d_in[5];  const float* se_c1b = (const float*)d_in[6];
  const float* se_c2w = (const float*)d_in[7];  const float* se_c2b = (const float*)d_in[8];
  const float* se_c3w = (const float*)d_in[9];  const float* se_c3b = (const float*)d_in[10];
  const float* se_fcw = (const float*)d_in[11]; const float* se_fcb = (const float*)d_in[12];
  const float* se_lnw = (const float*)d_in[13]; const float* se_lnb = (const float*)d_in[14];
  const float* ae_c1w = (const float*)d_in[15]; const float* ae_c1b = (const float*)d_in[16];
  const float* ae_c2w = (const float*)d_in[17]; const float* ae_c2b = (const float*)d_in[18];
  const float* ae_c3w = (const float*)d_in[19]; const float* ae_c3b = (const float*)d_in[20];
  const float* ae_fcw = (const float*)d_in[21]; const float* ae_fcb = (const float*)d_in[22];
  const float* ae_lnw = (const float*)d_in[23]; const float* ae_lnb = (const float*)d_in[24];
  const float* rtg_w1 = (const float*)d_in[25]; const float* rtg_b1 = (const float*)d_in[26];
  const float* rtg_w2 = (const float*)d_in[27]; const float* rtg_b2 = (const float*)d_in[28];
  const float* rtg_lnw= (const float*)d_in[29]; const float* rtg_lnb= (const float*)d_in[30];
  const float* ts_w1  = (const float*)d_in[31]; const float* ts_b1  = (const float*)d_in[32];
  const float* ts_w2  = (const float*)d_in[33]; const float* ts_b2  = (const float*)d_in[34];
  const float* ts_lnw = (const float*)d_in[35]; const float* ts_lnb = (const float*)d_in[36];
  const float* ip_w   = (const float*)d_in[37]; const float* ip_b   = (const float*)d_in[38];
  const float* lyr_wq = (const float*)d_in[39]; const float* lyr_bq = (const float*)d_in[40];
  const float* lyr_wk = (const float*)d_in[41]; const float* lyr_bk = (const float*)d_in[42];
  const float* lyr_wv = (const float*)d_in[43]; const float* lyr_bv = (const float*)d_in[44];
  const float* lyr_wo = (const float*)d_in[45]; const float* lyr_bo = (const float*)d_in[46];
  const float* lyr_f1w= (const float*)d_in[47]; const float* lyr_f1b= (const float*)d_in[48];
  const float* lyr_f2w= (const float*)d_in[49]; const float* lyr_f2b= (const float*)d_in[50];
  const float* lyr_l1w= (const float*)d_in[51]; const float* lyr_l1b= (const float*)d_in[52];
  const float* lyr_l2w= (const float*)d_in[53]; const float* lyr_l2b= (const float*)d_in[54];
  const float* ad_fcw = (const float*)d_in[55]; const float* ad_fcb = (const float*)d_in[56];
  const float* ad_w1  = (const float*)d_in[57]; const float* ad_b1  = (const float*)d_in[58];
  const float* ad_w2  = (const float*)d_in[59]; const float* ad_b2  = (const float*)d_in[60];
  const float* ad_w3  = (const float*)d_in[61]; const float* ad_b3  = (const float*)d_in[62];
  const float* sd_fcw = (const float*)d_in[63]; const float* sd_fcb = (const float*)d_in[64];
  const float* sd_w1  = (const float*)d_in[65]; const float* sd_b1  = (const float*)d_in[66];
  const float* sd_w2  = (const float*)d_in[67]; const float* sd_b2  = (const float*)d_in[68];
  const float* sd_w3  = (const float*)d_in[69]; const float* sd_b3  = (const float*)d_in[70];
  const float* rp_w   = (const float*)d_in[71]; const float* rp_b   = (const float*)d_in[72];

  float* ws = (float*)d_ws;
  long off = 0;
  auto alloc = [&](long n) { float* p = ws + off; off += n; return p; };

  float* region = alloc(10485760);
  float* h1 = region;
  float* h2 = region + 2097152;
  float* h3 = region + 6291456;
  float* s_emb = alloc(524288);
  float* a_emb = alloc(520192);
  float* r_emb = alloc(524288);
  float* t_emb = alloc(524288);
  float* etmp  = alloc(524288);
  float* xa = alloc(1568768);
  float* xb = alloc(1568768);
  float* qb = alloc(1568768);
  float* kb = alloc(1568768);
  float* vb = alloc(1568768);
  float* t2 = alloc(1568768);
  float* ffh = alloc(6275072);

  unsigned short* qbh = (unsigned short*)qb;
  unsigned short* kbh = (unsigned short*)kb;
  unsigned short* vbh = (unsigned short*)vb;

  unsigned short* bws = (unsigned short*)(ws + off);
  long boff = 0;
  auto ballo = [&](long n) { unsigned short* p = bws + boff; boff += n; return p; };
  unsigned short* ipW  = ballo(262144);
  unsigned short* wqW  = ballo(6L * 262144);
  unsigned short* wkW  = ballo(6L * 262144);
  unsigned short* wvW  = ballo(6L * 262144);
  unsigned short* woW  = ballo(6L * 262144);
  unsigned short* f1W  = ballo(6L * 1048576);
  unsigned short* f2W  = ballo(6L * 1048576);
  unsigned short* seW  = ballo(2097152);
  unsigned short* aeW  = ballo(2097152);
  unsigned short* rtgW = ballo(262144);
  unsigned short* tsW  = ballo(262144);
  unsigned short* adW  = ballo(262144);
  unsigned short* sdW  = ballo(262144);
  unsigned short* abuf = ballo(6275072);

  const long BT = (long)8 * TT;

  cast_bf(stream, ip_w,    ipW,  262144);
  cast_bf(stream, lyr_wq,  wqW,  6L * 262144);
  cast_bf(stream, lyr_wk,  wkW,  6L * 262144);
  cast_bf(stream, lyr_wv,  wvW,  6L * 262144);
  cast_bf(stream, lyr_wo,  woW,  6L * 262144);
  cast_bf(stream, lyr_f1w, f1W,  6L * 1048576);
  cast_bf(stream, lyr_f2w, f2W,  6L * 1048576);
  cast_bf(stream, se_fcw,  seW,  2097152);
  cast_bf(stream, ae_fcw,  aeW,  2097152);
  cast_bf(stream, rtg_w2,  rtgW, 262144);
  cast_bf(stream, ts_w2,   tsW,  262144);
  cast_bf(stream, ad_fcw,  adW,  262144);
  cast_bf(stream, sd_fcw,  sdW,  262144);

  conv3x3_kernel<14><<<dim3(1024, 1), 256, 0, stream>>>(states, se_c1w, se_c1b, h1, 32);
  conv3x3_kernel<32><<<dim3(1024, 2), 256, 0, stream>>>(h1, se_c2w, se_c2b, h2, 64);
  conv3x3_kernel<64><<<dim3(1024, 2), 256, 0, stream>>>(h2, se_c3w, se_c3b, h3, 64);
  cast_bf(stream, h3, abuf, 1024L * 4096);
  gemm_bf(stream, abuf, seW, se_fcb, etmp, 1024, 512, 4096);
  add_ln_kernel<<<1024, 256, 0, stream>>>(etmp, nullptr, se_lnw, se_lnb, s_emb);

  conv3x3_kernel<73><<<dim3(1016, 1), 256, 0, stream>>>(actions, ae_c1w, ae_c1b, h1, 32);
  conv3x3_kernel<32><<<dim3(1016, 2), 256, 0, stream>>>(h1, ae_c2w, ae_c2b, h2, 64);
  conv3x3_kernel<64><<<dim3(1016, 2), 256, 0, stream>>>(h2, ae_c3w, ae_c3b, h3, 64);
  cast_bf(stream, h3, abuf, 1016L * 4096);
  gemm_bf(stream, abuf, aeW, ae_fcb, etmp, 1016, 512, 4096);
  add_ln_kernel<<<1016, 256, 0, stream>>>(etmp, nullptr, ae_lnw, ae_lnb, a_emb);

  lin1_relu_kernel<<<(1024 * 512 + 255) / 256, 256, 0, stream>>>(rtgs, rtg_w1, rtg_b1, qb, 1024 * 512);
  cast_bf(stream, qb, abuf, 1024L * 512);
  gemm_bf(stream, abuf, rtgW, rtg_b2, etmp, 1024, 512, 512);
  add_ln_kernel<<<1024, 256, 0, stream>>>(etmp, nullptr, rtg_lnw, rtg_lnb, r_emb);

  lin1_relu_int_kernel<<<(1024 * 512 + 255) / 256, 256, 0, stream>>>(tsteps, ts_w1, ts_b1, qb, 1024 * 512);
  cast_bf(stream, qb, abuf, 1024L * 512);
  gemm_bf(stream, abuf, tsW, ts_b2, etmp, 1024, 512, 512);
  add_ln_kernel<<<1024, 256, 0, stream>>>(etmp, nullptr, ts_lnw, ts_lnb, t_emb);

  build_comb_kernel<<<(int)((8L * TT * 512 + 255) / 256), 256, 0, stream>>>(r_emb, s_emb, a_emb, t_emb, xb);
  cast_bf(stream, xb, abuf, BT * 512);
  gemm_bf(stream, abuf, ipW, ip_b, xa, (int)BT, 512, 512);

  for (int l = 0; l < 6; ++l) {
    const unsigned short* wq = wqW + (long)l * 262144; const float* bq = lyr_bq + (long)l * 512;
    const unsigned short* wk = wkW + (long)l * 262144; const float* bk = lyr_bk + (long)l * 512;
    const unsigned short* wv = wvW + (long)l * 262144; const float* bv = lyr_bv + (long)l * 512;
    const unsigned short* wo = woW + (long)l * 262144; const float* bo = lyr_bo + (long)l * 512;
    const unsigned short* f1w = f1W + (long)l * 1048576; const float* f1b = lyr_f1b + (long)l * 2048;
    const unsigned short* f2w = f2W + (long)l * 1048576; const float* f2b = lyr_f2b + (long)l * 512;
    const float* l1w = lyr_l1w + (long)l * 512; const float* l1b = lyr_l1b + (long)l * 512;
    const float* l2w = lyr_l2w + (long)l * 512; const float* l2b = lyr_l2b + (long)l * 512;

    cast_bf(stream, xa, abuf, BT * 512);
    gemm_bf(stream, abuf, wq, bq, (float*)qbh, (int)BT, 512, 512, 0, 1);
    gemm_bf(stream, abuf, wk, bk, (float*)kbh, (int)BT, 512, 512, 0, 1);
    gemm_bf(stream, abuf, wv, bv, (float*)vbh, (int)BT, 512, 512, 0, 1);

    attn_kernel<<<dim3(6, 64), 256, 0, stream>>>(qbh, kbh, vbh, abuf);

    gemm_bf(stream, abuf, wo, bo, t2, (int)BT, 512, 512);
    add_ln_kernel<<<(int)BT, 256, 0, stream>>>(xa, t2, l1w, l1b, xb);
    cast_bf(stream, xb, abuf, BT * 512);
    gemm_bf(stream, abuf, f1w, f1b, ffh, (int)BT, 2048, 512, 1);
    cast_bf(stream, ffh, abuf, BT * 2048);
    gemm_bf(stream, abuf, f2w, f2b, t2, (int)BT, 512, 2048);
    add_ln_kernel<<<(int)BT, 256, 0, stream>>>(xb, t2, l2w, l2b, xa);
  }

  float* outp = (float*)d_out;
  float* act_out = outp;
  float* st_out  = outp + 4784128;
  float* rw_out  = outp + 5701632;

  float* za  = region;
  float* zfc = region + 524288;
  float* dh1 = region + 1048576;
  float* dh2 = region + 2097152;

  gather3_kernel<<<(1024 * 512 + 255) / 256, 256, 0, stream>>>(xa, za, 1, 128);
  cast_bf(stream, za, abuf, 1024L * 512);
  gemm_bf(stream, abuf, adW, ad_fcb, zfc, 1024, 512, 512, 1);
  convT_fast_kernel<128, 2, 2, 1, 4><<<dim3(1024, 1), 256, 0, stream>>>(zfc, ad_w1, ad_b1, dh1, 64, 1);
  convT_fast_kernel<64, 4, 2, 1, 8><<<dim3(1024, 1), 256, 0, stream>>>(dh1, ad_w2, ad_b2, dh2, 32, 1);
  convT_fast_kernel<32, 8, 1, 0, 8><<<dim3(1024, 3), 256, 0, stream>>>(dh2, ad_w3, ad_b3, act_out, 73, 0);

  gather3_kernel<<<(1024 * 512 + 255) / 256, 256, 0, stream>>>(xa, za, 0, 128);
  cast_bf(stream, za, abuf, 1024L * 512);
  gemm_bf(stream, abuf, sdW, sd_fcb, zfc, 1024, 512, 512, 1);
  convT_fast_kernel<128, 2, 2, 1, 4><<<dim3(1024, 1), 256, 0, stream>>>(zfc, sd_w1, sd_b1, dh1, 64, 1);
  convT_fast_kernel<64, 4, 2, 1, 8><<<dim3(1024, 1), 256, 0, stream>>>(dh1, sd_w2, sd_b2, dh2, 32, 1);
  convT_fast_kernel<32, 8, 1, 0, 8><<<dim3(1024, 1), 256, 0, stream>>>(dh2, sd_w3, sd_b3, st_out, 14, 0);

  gather3_kernel<<<(1016 * 512 + 255) / 256, 256, 0, stream>>>(xa, za, 2, 127);
  reward_kernel<<<(1016 + 3) / 4, 256, 0, stream>>>(za, rp_w, rp_b, rw_out, 1016);
}

// Round 7
// 2057.577 us; speedup vs baseline: 2.0118x; 1.1835x over previous
//
#include <hip/hip_runtime.h>

// ---------------------------------------------------------------------------
// Decision-Transformer-like model. bf16-MFMA GEMMs + fused flash attention.
// B=8, L=128, D=512, H=8, DK=64, DFF=2048, NL=6, T=383, SC=14, AC=73
// Round 7: occupancy fix for skinny GEMMs -- split-K (atomicAdd epilogue),
//          merged QKV (N=1536), FFN1 bf16-out, add_ln dual fp32+bf16 output.
//          (Round 6 profile: 128x128 tiles gave FFN2 only 96 blocks = 0.4
//           waves/SIMD, 1.4% occupancy, 72 TF latency-bound.)
// ---------------------------------------------------------------------------

#define TT 383

typedef short      bf16x8 __attribute__((ext_vector_type(8)));
typedef float      f32x4  __attribute__((ext_vector_type(4)));
typedef unsigned short u16x8 __attribute__((ext_vector_type(8)));
typedef unsigned short u16x4 __attribute__((ext_vector_type(4)));

// ---------------- fp32 -> bf16 cast (RNE) -----------------------------------
__device__ __forceinline__ unsigned short f2bf(float f)
{
  unsigned u = __float_as_uint(f);
  return (unsigned short)((u + 0x7FFFu + ((u >> 16) & 1u)) >> 16);
}

__global__ __launch_bounds__(256) void cast_bf16_kernel(
    const float* __restrict__ in, unsigned short* __restrict__ out, long n)
{
  long i = ((long)blockIdx.x * 256 + threadIdx.x) * 4;
  if (i >= n) return;
  const float4 v = *(const float4*)(in + i);
  u16x4 o;
  o.x = f2bf(v.x); o.y = f2bf(v.y); o.z = f2bf(v.z); o.w = f2bf(v.w);
  *(u16x4*)(out + i) = o;
}

// merge wq/wk/wv (each [6][512][512]) -> [6][1536][512] bf16
__global__ __launch_bounds__(256) void merge_qkv_w_kernel(
    const float* __restrict__ wq, const float* __restrict__ wk,
    const float* __restrict__ wv, unsigned short* __restrict__ dst)
{
  long i = ((long)blockIdx.x * 256 + threadIdx.x) * 4;
  if (i >= 6L * 786432) return;
  long l = i / 786432, rem = i % 786432;
  int which = (int)(rem / 262144);
  long o = rem % 262144;
  const float* src = which == 0 ? wq : which == 1 ? wk : wv;
  float4 v = *(const float4*)(src + l * 262144 + o);
  u16x4 w;
  w.x = f2bf(v.x); w.y = f2bf(v.y); w.z = f2bf(v.z); w.w = f2bf(v.w);
  *(u16x4*)(dst + i) = w;
}

__global__ void merge_qkv_b_kernel(const float* __restrict__ bq, const float* __restrict__ bk,
                                   const float* __restrict__ bv, float* __restrict__ dst)
{
  int i = blockIdx.x * 256 + threadIdx.x;
  if (i >= 6 * 1536) return;
  int l = i / 1536, r = i % 1536;
  int which = r >> 9, o = r & 511;
  dst[i] = (which == 0 ? bq : which == 1 ? bk : bv)[l * 512 + o];
}

// ---------------- bf16 MFMA GEMM ---------------------------------------------
// A: [M,K] bf16 row-major. B: [N,K] bf16 row-major.
// splitK==1: C = A@B^T + bias (fp32, or bf16 if obf; optional relu).
// splitK>1 : C += partial via fp32 atomicAdd (C pre-zeroed); bias from z==0;
//            relu/obf unsupported (callers fold relu downstream).
#define LDAP 72
__global__ __launch_bounds__(256) void gemm_bf16_kernel(
    const unsigned short* __restrict__ A, const unsigned short* __restrict__ B,
    const float* __restrict__ bias, float* __restrict__ C,
    int M, int N, int K, int relu, int obf, int splitK)
{
  __shared__ __align__(16) unsigned short As[128 * LDAP];
  __shared__ __align__(16) unsigned short Bs[128 * LDAP];

  const int tid = threadIdx.x;
  const int lane = tid & 63;
  const int w  = tid >> 6;
  const int wr = w >> 1, wc = w & 1;
  const int m0 = blockIdx.x * 128, n0 = blockIdx.y * 128;
  const int z  = blockIdx.z;

  const int lr = lane & 15;
  const int hi = lane >> 4;

  f32x4 acc[4][4] = {};

  const int r = tid >> 1;
  const int h = tid & 1;

  int mrow = m0 + r; if (mrow >= M) mrow = M - 1;
  const unsigned short* Ap = A + (long)mrow * K + h * 32;
  const unsigned short* Bp = B + (long)(n0 + r) * K + h * 32;
  unsigned short* Asd = As + r * LDAP + h * 32;
  unsigned short* Bsd = Bs + r * LDAP + h * 32;

  const int kLen = K / splitK;
  const int kBeg = z * kLen, kEnd = kBeg + kLen;

  for (int k0 = kBeg; k0 < kEnd; k0 += 64) {
#pragma unroll
    for (int i = 0; i < 4; ++i)
      *(u16x8*)(Asd + i * 8) = *(const u16x8*)(Ap + k0 + i * 8);
#pragma unroll
    for (int i = 0; i < 4; ++i)
      *(u16x8*)(Bsd + i * 8) = *(const u16x8*)(Bp + k0 + i * 8);
    __syncthreads();

#pragma unroll
    for (int kk = 0; kk < 2; ++kk) {
      const int kof = kk * 32 + hi * 8;
      bf16x8 a[4], b[4];
#pragma unroll
      for (int t = 0; t < 4; ++t)
        a[t] = *(const bf16x8*)(As + (wr * 64 + t * 16 + lr) * LDAP + kof);
#pragma unroll
      for (int t = 0; t < 4; ++t)
        b[t] = *(const bf16x8*)(Bs + (wc * 64 + t * 16 + lr) * LDAP + kof);
#pragma unroll
      for (int i = 0; i < 4; ++i)
#pragma unroll
        for (int j = 0; j < 4; ++j)
          acc[i][j] = __builtin_amdgcn_mfma_f32_16x16x32_bf16(a[i], b[j], acc[i][j], 0, 0, 0);
    }
    __syncthreads();
  }

  // C/D layout (HW-verified m89): col = lane&15, row = (lane>>4)*4 + reg
#pragma unroll
  for (int j = 0; j < 4; ++j) {
    const int col = n0 + wc * 64 + j * 16 + lr;
    const float bv = (bias && z == 0) ? bias[col] : 0.f;
#pragma unroll
    for (int i = 0; i < 4; ++i) {
#pragma unroll
      for (int v = 0; v < 4; ++v) {
        int row = m0 + wr * 64 + i * 16 + hi * 4 + v;
        if (row < M) {
          float x = acc[i][j][v] + bv;
          if (splitK > 1) {
            atomicAdd(&C[(long)row * N + col], x);
          } else {
            if (relu) x = fmaxf(x, 0.f);
            if (obf) ((unsigned short*)C)[(long)row * N + col] = f2bf(x);
            else     C[(long)row * N + col] = x;
          }
        }
      }
    }
  }
}

static inline void gemm_bf(hipStream_t st, const unsigned short* A, const unsigned short* B,
                           const float* bias, float* C, int M, int N, int K,
                           int relu = 0, int obf = 0)
{
  dim3 g((M + 127) / 128, N / 128, 1);
  gemm_bf16_kernel<<<g, 256, 0, st>>>(A, B, bias, C, M, N, K, relu, obf, 1);
}

static inline void gemm_sk(hipStream_t st, const unsigned short* A, const unsigned short* B,
                           const float* bias, float* C, int M, int N, int K, int S)
{
  hipMemsetAsync(C, 0, (size_t)M * N * 4, st);
  dim3 g((M + 127) / 128, N / 128, S);
  gemm_bf16_kernel<<<g, 256, 0, st>>>(A, B, bias, C, M, N, K, 0, 0, S);
}

static inline void cast_bf(hipStream_t st, const float* in, unsigned short* out, long n)
{
  cast_bf16_kernel<<<(int)((n / 4 + 255) / 256), 256, 0, st>>>(in, out, n);
}

// ---------------- fused causal flash attention ------------------------------
// Qkv: bf16 [B*383][1536] (Q cols 0-511, K 512-1023, V 1024-1535), head h at
// +h*64. O: bf16 [B*383][512]. scale=0.125. Grid (6 q-tiles, 64 bh), 4 waves.
__global__ __launch_bounds__(256) void attn_kernel(
    const unsigned short* __restrict__ Qkv, unsigned short* __restrict__ Ob)
{
  __shared__ __align__(16) unsigned short Kl[32 * 72];
  __shared__ __align__(16) unsigned short Vt[64 * 40];
  __shared__ __align__(16) unsigned short Pl[4][16 * 40];

  const int tid = threadIdx.x;
  const int lane = tid & 63;
  const int w = tid >> 6;
  const int lr = lane & 15, hi = lane >> 4;
  const int q0 = blockIdx.x * 64;
  const int bh = blockIdx.y;
  const int b = bh >> 3, h = bh & 7;
  const long baseq = (long)b * TT * 1536 + h * 64;
  const long baseo = (long)b * TT * 512 + h * 64;

  const int qrow = q0 + w * 16 + lr;
  const int qr_c = qrow < TT ? qrow : TT - 1;
  bf16x8 qf0 = *(const bf16x8*)(Qkv + baseq + (long)qr_c * 1536 + hi * 8);
  bf16x8 qf1 = *(const bf16x8*)(Qkv + baseq + (long)qr_c * 1536 + 32 + hi * 8);

  float m[4], l[4];
  f32x4 acc[4];
#pragma unroll
  for (int r = 0; r < 4; ++r) { m[r] = -1e30f; l[r] = 0.f; }
#pragma unroll
  for (int c = 0; c < 4; ++c) acc[c] = (f32x4){0.f, 0.f, 0.f, 0.f};

  const int qmax = min(q0 + 63, TT - 1);
  const int nkv = qmax + 1;

  for (int kv0 = 0; kv0 < nkv; kv0 += 32) {
    __syncthreads();
    {
      int e = tid * 8;
      int kv = e >> 6, d = e & 63;
      int skv = kv0 + kv; if (skv >= TT) skv = TT - 1;
      *(u16x8*)(Kl + kv * 72 + d) = *(const u16x8*)(Qkv + baseq + 512 + (long)skv * 1536 + d);
      u16x8 vv = *(const u16x8*)(Qkv + baseq + 1024 + (long)skv * 1536 + d);
#pragma unroll
      for (int j = 0; j < 8; ++j) Vt[(d + j) * 40 + kv] = vv[j];
    }
    __syncthreads();

    f32x4 s[2] = {};
#pragma unroll
    for (int t = 0; t < 2; ++t) {
      bf16x8 k0 = *(const bf16x8*)(Kl + (t * 16 + lr) * 72 + hi * 8);
      bf16x8 k1 = *(const bf16x8*)(Kl + (t * 16 + lr) * 72 + 32 + hi * 8);
      s[t] = __builtin_amdgcn_mfma_f32_16x16x32_bf16(qf0, k0, s[t], 0, 0, 0);
      s[t] = __builtin_amdgcn_mfma_f32_16x16x32_bf16(qf1, k1, s[t], 0, 0, 0);
    }

    const int qq = q0 + w * 16 + hi * 4;
#pragma unroll
    for (int r = 0; r < 4; ++r) {
      float v0 = s[0][r] * 0.125f;
      float v1 = s[1][r] * 0.125f;
      const int qr = qq + r;
      const int kvA = kv0 + lr, kvB = kv0 + 16 + lr;
      if (kvA > qr || kvA >= TT) v0 = -1e30f;
      if (kvB > qr || kvB >= TT) v1 = -1e30f;
      float rm = fmaxf(v0, v1);
      rm = fmaxf(rm, __shfl_xor(rm, 1));
      rm = fmaxf(rm, __shfl_xor(rm, 2));
      rm = fmaxf(rm, __shfl_xor(rm, 4));
      rm = fmaxf(rm, __shfl_xor(rm, 8));
      float mn = fmaxf(m[r], rm);
      float al = expf(m[r] - mn);
      float e0 = expf(v0 - mn);
      float e1 = expf(v1 - mn);
      float rs = e0 + e1;
      rs += __shfl_xor(rs, 1);
      rs += __shfl_xor(rs, 2);
      rs += __shfl_xor(rs, 4);
      rs += __shfl_xor(rs, 8);
      l[r] = l[r] * al + rs;
      m[r] = mn;
#pragma unroll
      for (int c = 0; c < 4; ++c) acc[c][r] *= al;
      Pl[w][(hi * 4 + r) * 40 + lr]      = f2bf(e0);
      Pl[w][(hi * 4 + r) * 40 + 16 + lr] = f2bf(e1);
    }

    bf16x8 pa = *(const bf16x8*)(&Pl[w][lr * 40 + hi * 8]);
#pragma unroll
    for (int c = 0; c < 4; ++c) {
      bf16x8 vf = *(const bf16x8*)(Vt + (c * 16 + lr) * 40 + hi * 8);
      acc[c] = __builtin_amdgcn_mfma_f32_16x16x32_bf16(pa, vf, acc[c], 0, 0, 0);
    }
  }

  float inv[4];
#pragma unroll
  for (int r = 0; r < 4; ++r) inv[r] = 1.0f / l[r];
#pragma unroll
  for (int c = 0; c < 4; ++c) {
#pragma unroll
    for (int r = 0; r < 4; ++r) {
      int qr = q0 + w * 16 + hi * 4 + r;
      if (qr < TT) Ob[baseo + (long)qr * 512 + c * 16 + lr] = f2bf(acc[c][r] * inv[r]);
    }
  }
}

// ---------------- direct 3x3 conv (pad 1, 8x8, relu) ------------------------
template <int CIN>
__global__ __launch_bounds__(256) void conv3x3_kernel(
    const float* __restrict__ in, const float* __restrict__ w,
    const float* __restrict__ bias, float* __restrict__ out, int Cout)
{
  __shared__ float img[CIN * 100];
  const int n = blockIdx.x;
  const int tid = threadIdx.x;
  for (int i = tid; i < CIN * 100; i += 256) img[i] = 0.f;
  __syncthreads();
  const float* src = in + (long)n * CIN * 64;
  for (int i = tid; i < CIN * 64; i += 256) {
    int ic = i >> 6, p = i & 63;
    img[ic * 100 + ((p >> 3) + 1) * 10 + (p & 7) + 1] = src[i];
  }
  __syncthreads();

  const int y  = tid & 7;
  const int oc = blockIdx.y * 32 + (tid >> 3);
  if (oc >= Cout) return;

  float acc[8];
#pragma unroll
  for (int x = 0; x < 8; ++x) acc[x] = bias[oc];

  const float* wp = w + (long)oc * CIN * 9;
  for (int ic = 0; ic < CIN; ++ic) {
    float wr[9];
#pragma unroll
    for (int q = 0; q < 9; ++q) wr[q] = wp[ic * 9 + q];
    const float* ib = &img[ic * 100 + y * 10];
#pragma unroll
    for (int ky = 0; ky < 3; ++ky) {
      const float* r = ib + ky * 10;
      float c0 = r[0], c1 = r[1];
#pragma unroll
      for (int x = 0; x < 8; ++x) {
        float c2 = r[x + 2];
        acc[x] = fmaf(c0, wr[ky * 3 + 0],
                 fmaf(c1, wr[ky * 3 + 1],
                 fmaf(c2, wr[ky * 3 + 2], acc[x])));
        c0 = c1; c1 = c2;
      }
    }
  }
  float* dst = out + ((long)n * Cout + oc) * 64 + y * 8;
#pragma unroll
  for (int x = 0; x < 8; ++x) dst[x] = fmaxf(acc[x], 0.f);
}

// ---------------- transposed conv as dilated conv3x3 ------------------------
// inRelu: apply relu to the staged input (folds producer's deferred relu).
template <int CIN, int IH, int S, int OP, int OH>
__global__ __launch_bounds__(256) void convT_fast_kernel(
    const float* __restrict__ in, const float* __restrict__ w,
    const float* __restrict__ bias, float* __restrict__ out,
    int Cout, int relu, int inRelu)
{
  constexpr int DW = (IH - 1) * S + 3 + OP;
  constexpr int OCPB = 256 / OH;
  __shared__ float img[CIN * DW * DW];

  const int n = blockIdx.x;
  const int tid = threadIdx.x;
  for (int i = tid; i < CIN * DW * DW; i += 256) img[i] = 0.f;
  __syncthreads();
  const float* src = in + (long)n * CIN * IH * IH;
  for (int i = tid; i < CIN * IH * IH; i += 256) {
    int ic = i / (IH * IH), p = i % (IH * IH);
    int iy = p / IH, ix = p % IH;
    float v = src[i];
    if (inRelu) v = fmaxf(v, 0.f);
    img[ic * DW * DW + (1 + iy * S) * DW + (1 + ix * S)] = v;
  }
  __syncthreads();

  const int y  = tid % OH;
  const int oc = blockIdx.y * OCPB + tid / OH;
  if (oc >= Cout) return;

  float acc[OH];
#pragma unroll
  for (int x = 0; x < OH; ++x) acc[x] = bias[oc];

  for (int ic = 0; ic < CIN; ++ic) {
    const float* wp = w + ((long)ic * Cout + oc) * 9;
    float wr[9];
#pragma unroll
    for (int q = 0; q < 9; ++q) wr[q] = wp[8 - q];
    const float* ib = &img[ic * DW * DW + y * DW];
#pragma unroll
    for (int ky = 0; ky < 3; ++ky) {
      const float* r = ib + ky * DW;
      float c0 = r[0], c1 = r[1];
#pragma unroll
      for (int x = 0; x < OH; ++x) {
        float c2 = r[x + 2];
        acc[x] = fmaf(c0, wr[ky * 3 + 0],
                 fmaf(c1, wr[ky * 3 + 1],
                 fmaf(c2, wr[ky * 3 + 2], acc[x])));
        c0 = c1; c1 = c2;
      }
    }
  }
  float* dst = out + ((long)n * Cout + oc) * OH * OH + y * OH;
#pragma unroll
  for (int x = 0; x < OH; ++x) dst[x] = relu ? fmaxf(acc[x], 0.f) : acc[x];
}

// ---------------- LayerNorm (D=512), residual add, dual fp32+bf16 out -------
__device__ __forceinline__ float blockReduceSum256(float v)
{
  __shared__ float sb[4];
  int lane = threadIdx.x & 63, wid = threadIdx.x >> 6;
#pragma unroll
  for (int o = 32; o; o >>= 1) v += __shfl_down(v, o);
  __syncthreads();
  if (lane == 0) sb[wid] = v;
  __syncthreads();
  return sb[0] + sb[1] + sb[2] + sb[3];
}

__global__ __launch_bounds__(256) void add_ln_kernel(
    const float* __restrict__ a, const float* __restrict__ b,
    const float* __restrict__ w, const float* __restrict__ bb,
    float* __restrict__ out, unsigned short* __restrict__ outbf)
{
  long row = blockIdx.x;
  const float* pa = a + row * 512;
  float x0 = pa[threadIdx.x], x1 = pa[threadIdx.x + 256];
  if (b) {
    const float* pb = b + row * 512;
    x0 += pb[threadIdx.x]; x1 += pb[threadIdx.x + 256];
  }
  float mean = blockReduceSum256(x0 + x1) * (1.f / 512.f);
  float d0 = x0 - mean, d1 = x1 - mean;
  float var = blockReduceSum256(d0 * d0 + d1 * d1) * (1.f / 512.f);
  float inv = 1.0f / sqrtf(var + 1e-5f);
  float v0 = d0 * inv * w[threadIdx.x] + bb[threadIdx.x];
  float v1 = d1 * inv * w[threadIdx.x + 256] + bb[threadIdx.x + 256];
  float* po = out + row * 512;
  po[threadIdx.x]       = v0;
  po[threadIdx.x + 256] = v1;
  if (outbf) {
    outbf[row * 512 + threadIdx.x]       = f2bf(v0);
    outbf[row * 512 + threadIdx.x + 256] = f2bf(v1);
  }
}

// ---------------- small elementwise kernels ---------------------------------
__global__ void lin1_relu_kernel(const float* __restrict__ x, const float* __restrict__ w,
                                 const float* __restrict__ b, float* __restrict__ out, long total)
{
  long idx = (long)blockIdx.x * 256 + threadIdx.x;
  if (idx >= total) return;
  int d = idx & 511; long r = idx >> 9;
  out[idx] = fmaxf(fmaf(x[r], w[d], b[d]), 0.f);
}

__global__ void lin1_relu_int_kernel(const int* __restrict__ x, const float* __restrict__ w,
                                     const float* __restrict__ b, float* __restrict__ out, long total)
{
  long idx = (long)blockIdx.x * 256 + threadIdx.x;
  if (idx >= total) return;
  int d = idx & 511; long r = idx >> 9;
  out[idx] = fmaxf(fmaf((float)x[r], w[d], b[d]), 0.f);
}

__global__ void build_comb_kernel(const float* __restrict__ r, const float* __restrict__ s,
                                  const float* __restrict__ a, const float* __restrict__ t,
                                  float* __restrict__ comb)
{
  long idx = (long)blockIdx.x * 256 + threadIdx.x;
  if (idx >= (long)8 * TT * 512) return;
  int d = idx & 511;
  long rr = idx >> 9;
  int tok = (int)(rr % TT);
  int b   = (int)(rr / TT);
  int grp = tok / 3, ph = tok % 3;
  float te = t[((long)b * 128 + grp) * 512 + d];
  float v;
  if (ph == 0)      v = r[((long)b * 128 + grp) * 512 + d] + te;
  else if (ph == 1) v = s[((long)b * 128 + grp) * 512 + d] + te;
  else              v = a[((long)b * 127 + grp) * 512 + d] + te;
  comb[idx] = v;
}

__global__ void gather3_kernel(const float* __restrict__ x, float* __restrict__ out,
                               int offset, int count)
{
  long idx = (long)blockIdx.x * 256 + threadIdx.x;
  long total = (long)8 * count * 512;
  if (idx >= total) return;
  int d = idx & 511;
  long r = idx >> 9;
  int i = (int)(r % count);
  int b = (int)(r / count);
  out[idx] = x[((long)b * TT + offset + 3 * i) * 512 + d];
}

__global__ __launch_bounds__(256) void reward_kernel(const float* __restrict__ x,
                                                     const float* __restrict__ w,
                                                     const float* __restrict__ b,
                                                     float* __restrict__ out, int rows)
{
  int row = blockIdx.x * 4 + (threadIdx.x >> 6);
  int lane = threadIdx.x & 63;
  if (row >= rows) return;
  const float* p = x + (long)row * 512;
  float s = 0.f;
  for (int j = lane; j < 512; j += 64) s = fmaf(p[j], w[j], s);
#pragma unroll
  for (int o = 32; o; o >>= 1) s += __shfl_xor(s, o);
  if (lane == 0) out[row] = s + b[0];
}

// ---------------------------------------------------------------------------
extern "C" void kernel_launch(void* const* d_in, const int* in_sizes, int n_in,
                              void* d_out, int out_size, void* d_ws, size_t ws_size,
                              hipStream_t stream)
{
  const float* states  = (const float*)d_in[0];
  const float* rtgs    = (const float*)d_in[1];
  const int*   tsteps  = (const int*)d_in[2];
  const float* actions = (const float*)d_in[3];
  // d_in[4] mask: tril, hardcoded causal
  const float* se_c1w = (const float*)d_in[5];  const float* se_c1b = (const float*)d_in[6];
  const float* se_c2w = (const float*)d_in[7];  const float* se_c2b = (const float*)d_in[8];
  const float* se_c3w = (const float*)d_in[9];  const float* se_c3b = (const float*)d_in[10];
  const float* se_fcw = (const float*)d_in[11]; const float* se_fcb = (const float*)d_in[12];
  const float* se_lnw = (const float*)d_in[13]; const float* se_lnb = (const float*)d_in[14];
  const float* ae_c1w = (const float*)d_in[15]; const float* ae_c1b = (const float*)d_in[16];
  const float* ae_c2w = (const float*)d_in[17]; const float* ae_c2b = (const float*)d_in[18];
  const float* ae_c3w = (const float*)d_in[19]; const float* ae_c3b = (const float*)d_in[20];
  const float* ae_fcw = (const float*)d_in[21]; const float* ae_fcb = (const float*)d_in[22];
  const float* ae_lnw = (const float*)d_in[23]; const float* ae_lnb = (const float*)d_in[24];
  const float* rtg_w1 = (const float*)d_in[25]; const float* rtg_b1 = (const float*)d_in[26];
  const float* rtg_w2 = (const float*)d_in[27]; const float* rtg_b2 = (const float*)d_in[28];
  const float* rtg_lnw= (const float*)d_in[29]; const float* rtg_lnb= (const float*)d_in[30];
  const float* ts_w1  = (const float*)d_in[31]; const float* ts_b1  = (const float*)d_in[32];
  const float* ts_w2  = (const float*)d_in[33]; const float* ts_b2  = (const float*)d_in[34];
  const float* ts_lnw = (const float*)d_in[35]; const float* ts_lnb = (const float*)d_in[36];
  const float* ip_w   = (const float*)d_in[37]; const float* ip_b   = (const float*)d_in[38];
  const float* lyr_wq = (const float*)d_in[39]; const float* lyr_bq = (const float*)d_in[40];
  const float* lyr_wk = (const float*)d_in[41]; const float* lyr_bk = (const float*)d_in[42];
  const float* lyr_wv = (const float*)d_in[43]; const float* lyr_bv = (const float*)d_in[44];
  const float* lyr_wo = (const float*)d_in[45]; const float* lyr_bo = (const float*)d_in[46];
  const float* lyr_f1w= (const float*)d_in[47]; const float* lyr_f1b= (const float*)d_in[48];
  const float* lyr_f2w= (const float*)d_in[49]; const float* lyr_f2b= (const float*)d_in[50];
  const float* lyr_l1w= (const float*)d_in[51]; const float* lyr_l1b= (const float*)d_in[52];
  const float* lyr_l2w= (const float*)d_in[53]; const float* lyr_l2b= (const float*)d_in[54];
  const float* ad_fcw = (const float*)d_in[55]; const float* ad_fcb = (const float*)d_in[56];
  const float* ad_w1  = (const float*)d_in[57]; const float* ad_b1  = (const float*)d_in[58];
  const float* ad_w2  = (const float*)d_in[59]; const float* ad_b2  = (const float*)d_in[60];
  const float* ad_w3  = (const float*)d_in[61]; const float* ad_b3  = (const float*)d_in[62];
  const float* sd_fcw = (const float*)d_in[63]; const float* sd_fcb = (const float*)d_in[64];
  const float* sd_w1  = (const float*)d_in[65]; const float* sd_b1  = (const float*)d_in[66];
  const float* sd_w2  = (const float*)d_in[67]; const float* sd_b2  = (const float*)d_in[68];
  const float* sd_w3  = (const float*)d_in[69]; const float* sd_b3  = (const float*)d_in[70];
  const float* rp_w   = (const float*)d_in[71]; const float* rp_b   = (const float*)d_in[72];

  float* ws = (float*)d_ws;
  long off = 0;
  auto alloc = [&](long n) { float* p = ws + off; off += n; return p; };

  float* region = alloc(10485760);           // conv / decoder scratch
  float* h1 = region;
  float* h2 = region + 2097152;
  float* h3 = region + 6291456;
  float* s_emb = alloc(524288);
  float* a_emb = alloc(520192);
  float* r_emb = alloc(524288);
  float* t_emb = alloc(524288);
  float* etmp  = alloc(524288);
  float* xa = alloc(1568768);
  float* xb = alloc(1568768);
  float* t2 = alloc(1568768);
  float* qkvB = alloc(9216);                 // merged QKV bias [6][1536]

  unsigned short* bws = (unsigned short*)(ws + off);
  long boff = 0;
  auto ballo = [&](long n) { unsigned short* p = bws + boff; boff += n; return p; };
  unsigned short* ipW   = ballo(262144);
  unsigned short* wqkvW = ballo(6L * 786432);    // [6][1536][512]
  unsigned short* woW   = ballo(6L * 262144);
  unsigned short* f1W   = ballo(6L * 1048576);
  unsigned short* f2W   = ballo(6L * 1048576);
  unsigned short* seW   = ballo(2097152);
  unsigned short* aeW   = ballo(2097152);
  unsigned short* rtgW  = ballo(262144);
  unsigned short* tsW   = ballo(262144);
  unsigned short* adW   = ballo(262144);
  unsigned short* sdW   = ballo(262144);
  unsigned short* qkvbf = ballo(4706304);        // [BT][1536]
  unsigned short* aobf  = ballo(1568768);        // attn out bf16
  unsigned short* xbfA  = ballo(1568768);        // bf16(xa)
  unsigned short* xbfB  = ballo(1568768);        // bf16(xb)
  unsigned short* ffhbf = ballo(6275072);        // FFN hidden bf16
  unsigned short* abuf  = ballo(6275072);        // general cast scratch

  const long BT = (long)8 * TT;                  // 3064

  // ---------------- weight pre-casts / merges ----------------
  cast_bf(stream, ip_w,    ipW,  262144);
  merge_qkv_w_kernel<<<(int)((6L * 786432 / 4 + 255) / 256), 256, 0, stream>>>(lyr_wq, lyr_wk, lyr_wv, wqkvW);
  merge_qkv_b_kernel<<<(6 * 1536 + 255) / 256, 256, 0, stream>>>(lyr_bq, lyr_bk, lyr_bv, qkvB);
  cast_bf(stream, lyr_wo,  woW,  6L * 262144);
  cast_bf(stream, lyr_f1w, f1W,  6L * 1048576);
  cast_bf(stream, lyr_f2w, f2W,  6L * 1048576);
  cast_bf(stream, se_fcw,  seW,  2097152);
  cast_bf(stream, ae_fcw,  aeW,  2097152);
  cast_bf(stream, rtg_w2,  rtgW, 262144);
  cast_bf(stream, ts_w2,   tsW,  262144);
  cast_bf(stream, ad_fcw,  adW,  262144);
  cast_bf(stream, sd_fcw,  sdW,  262144);

  // ---------------- encoders ----------------
  conv3x3_kernel<14><<<dim3(1024, 1), 256, 0, stream>>>(states, se_c1w, se_c1b, h1, 32);
  conv3x3_kernel<32><<<dim3(1024, 2), 256, 0, stream>>>(h1, se_c2w, se_c2b, h2, 64);
  conv3x3_kernel<64><<<dim3(1024, 2), 256, 0, stream>>>(h2, se_c3w, se_c3b, h3, 64);
  cast_bf(stream, h3, abuf, 1024L * 4096);
  gemm_sk(stream, abuf, seW, se_fcb, etmp, 1024, 512, 4096, 8);
  add_ln_kernel<<<1024, 256, 0, stream>>>(etmp, nullptr, se_lnw, se_lnb, s_emb, nullptr);

  conv3x3_kernel<73><<<dim3(1016, 1), 256, 0, stream>>>(actions, ae_c1w, ae_c1b, h1, 32);
  conv3x3_kernel<32><<<dim3(1016, 2), 256, 0, stream>>>(h1, ae_c2w, ae_c2b, h2, 64);
  conv3x3_kernel<64><<<dim3(1016, 2), 256, 0, stream>>>(h2, ae_c3w, ae_c3b, h3, 64);
  cast_bf(stream, h3, abuf, 1016L * 4096);
  gemm_sk(stream, abuf, aeW, ae_fcb, etmp, 1016, 512, 4096, 8);
  add_ln_kernel<<<1016, 256, 0, stream>>>(etmp, nullptr, ae_lnw, ae_lnb, a_emb, nullptr);

  lin1_relu_kernel<<<(1024 * 512 + 255) / 256, 256, 0, stream>>>(rtgs, rtg_w1, rtg_b1, t2, 1024 * 512);
  cast_bf(stream, t2, abuf, 1024L * 512);
  gemm_sk(stream, abuf, rtgW, rtg_b2, etmp, 1024, 512, 512, 8);
  add_ln_kernel<<<1024, 256, 0, stream>>>(etmp, nullptr, rtg_lnw, rtg_lnb, r_emb, nullptr);

  lin1_relu_int_kernel<<<(1024 * 512 + 255) / 256, 256, 0, stream>>>(tsteps, ts_w1, ts_b1, t2, 1024 * 512);
  cast_bf(stream, t2, abuf, 1024L * 512);
  gemm_sk(stream, abuf, tsW, ts_b2, etmp, 1024, 512, 512, 8);
  add_ln_kernel<<<1024, 256, 0, stream>>>(etmp, nullptr, ts_lnw, ts_lnb, t_emb, nullptr);

  build_comb_kernel<<<(int)((8L * TT * 512 + 255) / 256), 256, 0, stream>>>(r_emb, s_emb, a_emb, t_emb, xb);
  cast_bf(stream, xb, abuf, BT * 512);
  gemm_sk(stream, abuf, ipW, ip_b, xa, (int)BT, 512, 512, 4);
  cast_bf(stream, xa, xbfA, BT * 512);

  // ---------------- transformer layers ----------------
  for (int l = 0; l < 6; ++l) {
    const unsigned short* wqkv = wqkvW + (long)l * 786432;
    const float* bqkv = qkvB + (long)l * 1536;
    const unsigned short* wo = woW + (long)l * 262144; const float* bo = lyr_bo + (long)l * 512;
    const unsigned short* f1w = f1W + (long)l * 1048576; const float* f1b = lyr_f1b + (long)l * 2048;
    const unsigned short* f2w = f2W + (long)l * 1048576; const float* f2b = lyr_f2b + (long)l * 512;
    const float* l1w = lyr_l1w + (long)l * 512; const float* l1b = lyr_l1b + (long)l * 512;
    const float* l2w = lyr_l2w + (long)l * 512; const float* l2b = lyr_l2b + (long)l * 512;

    gemm_bf(stream, xbfA, wqkv, bqkv, (float*)qkvbf, (int)BT, 1536, 512, 0, 1);  // 288 blocks
    attn_kernel<<<dim3(6, 64), 256, 0, stream>>>(qkvbf, aobf);
    gemm_sk(stream, aobf, wo, bo, t2, (int)BT, 512, 512, 4);                      // 384 blocks
    add_ln_kernel<<<(int)BT, 256, 0, stream>>>(xa, t2, l1w, l1b, xb, xbfB);
    gemm_bf(stream, xbfB, f1w, f1b, (float*)ffhbf, (int)BT, 2048, 512, 1, 1);     // 384 blocks
    gemm_sk(stream, ffhbf, f2w, f2b, t2, (int)BT, 512, 2048, 4);                  // 384 blocks
    add_ln_kernel<<<(int)BT, 256, 0, stream>>>(xb, t2, l2w, l2b, xa, xbfA);
  }

  // ---------------- decoders ----------------
  float* outp = (float*)d_out;
  float* act_out = outp;              // 8*128*73*64 = 4,784,128
  float* st_out  = outp + 4784128;    // 8*128*14*64 = 917,504
  float* rw_out  = outp + 5701632;    // 8*127 = 1016

  float* za  = region;
  float* zfc = region + 524288;
  float* dh1 = region + 1048576;
  float* dh2 = region + 2097152;

  gather3_kernel<<<(1024 * 512 + 255) / 256, 256, 0, stream>>>(xa, za, 1, 128);
  cast_bf(stream, za, abuf, 1024L * 512);
  gemm_sk(stream, abuf, adW, ad_fcb, zfc, 1024, 512, 512, 8);   // relu folded into convT load
  convT_fast_kernel<128, 2, 2, 1, 4><<<dim3(1024, 1), 256, 0, stream>>>(zfc, ad_w1, ad_b1, dh1, 64, 1, 1);
  convT_fast_kernel<64, 4, 2, 1, 8><<<dim3(1024, 1), 256, 0, stream>>>(dh1, ad_w2, ad_b2, dh2, 32, 1, 0);
  convT_fast_kernel<32, 8, 1, 0, 8><<<dim3(1024, 3), 256, 0, stream>>>(dh2, ad_w3, ad_b3, act_out, 73, 0, 0);

  gather3_kernel<<<(1024 * 512 + 255) / 256, 256, 0, stream>>>(xa, za, 0, 128);
  cast_bf(stream, za, abuf, 1024L * 512);
  gemm_sk(stream, abuf, sdW, sd_fcb, zfc, 1024, 512, 512, 8);
  convT_fast_kernel<128, 2, 2, 1, 4><<<dim3(1024, 1), 256, 0, stream>>>(zfc, sd_w1, sd_b1, dh1, 64, 1, 1);
  convT_fast_kernel<64, 4, 2, 1, 8><<<dim3(1024, 1), 256, 0, stream>>>(dh1, sd_w2, sd_b2, dh2, 32, 1, 0);
  convT_fast_kernel<32, 8, 1, 0, 8><<<dim3(1024, 1), 256, 0, stream>>>(dh2, sd_w3, sd_b3, st_out, 14, 0, 0);

  gather3_kernel<<<(1016 * 512 + 255) / 256, 256, 0, stream>>>(xa, za, 2, 127);
  reward_kernel<<<(1016 + 3) / 4, 256, 0, stream>>>(za, rp_w, rp_b, rw_out, 1016);
}

// Round 9
// 1997.362 us; speedup vs baseline: 2.0724x; 1.0301x over previous
//
#include <hip/hip_runtime.h>

// ---------------------------------------------------------------------------
// Decision-Transformer-like model. bf16-MFMA GEMMs + MFMA convs + flash attn.
// B=8, L=128, D=512, H=8, DK=64, DFF=2048, NL=6, T=383, SC=14, AC=73
// Round 9 (= round 8 resubmit after GPU timeout; code audited, no changes):
//          encoder conv3x3 -> bf16 MFMA implicit-GEMM (channel-last padded
//          layout, 9 accumulating taps; was 340us of fp32 VALU at MfmaUtil 0).
//          FC weights column-permuted to consume conv3's pixel-major output.
//          lin1/build_comb emit bf16 directly. FFN2 split-K 4->8.
// ---------------------------------------------------------------------------

#define TT 383

typedef short      bf16x8 __attribute__((ext_vector_type(8)));
typedef float      f32x4  __attribute__((ext_vector_type(4)));
typedef unsigned short u16x8 __attribute__((ext_vector_type(8)));
typedef unsigned short u16x4 __attribute__((ext_vector_type(4)));

// ---------------- fp32 -> bf16 cast (RNE) -----------------------------------
__device__ __forceinline__ unsigned short f2bf(float f)
{
  unsigned u = __float_as_uint(f);
  return (unsigned short)((u + 0x7FFFu + ((u >> 16) & 1u)) >> 16);
}

__global__ __launch_bounds__(256) void cast_bf16_kernel(
    const float* __restrict__ in, unsigned short* __restrict__ out, long n)
{
  long i = ((long)blockIdx.x * 256 + threadIdx.x) * 4;
  if (i >= n) return;
  const float4 v = *(const float4*)(in + i);
  u16x4 o;
  o.x = f2bf(v.x); o.y = f2bf(v.y); o.z = f2bf(v.z); o.w = f2bf(v.w);
  *(u16x4*)(out + i) = o;
}

// merge wq/wk/wv (each [6][512][512]) -> [6][1536][512] bf16
__global__ __launch_bounds__(256) void merge_qkv_w_kernel(
    const float* __restrict__ wq, const float* __restrict__ wk,
    const float* __restrict__ wv, unsigned short* __restrict__ dst)
{
  long i = ((long)blockIdx.x * 256 + threadIdx.x) * 4;
  if (i >= 6L * 786432) return;
  long l = i / 786432, rem = i % 786432;
  int which = (int)(rem / 262144);
  long o = rem % 262144;
  const float* src = which == 0 ? wq : which == 1 ? wk : wv;
  float4 v = *(const float4*)(src + l * 262144 + o);
  u16x4 w;
  w.x = f2bf(v.x); w.y = f2bf(v.y); w.z = f2bf(v.z); w.w = f2bf(v.w);
  *(u16x4*)(dst + i) = w;
}

__global__ void merge_qkv_b_kernel(const float* __restrict__ bq, const float* __restrict__ bk,
                                   const float* __restrict__ bv, float* __restrict__ dst)
{
  int i = blockIdx.x * 256 + threadIdx.x;
  if (i >= 6 * 1536) return;
  int l = i / 1536, r = i % 1536;
  int which = r >> 9, o = r & 511;
  dst[i] = (which == 0 ? bq : which == 1 ? bk : bv)[l * 512 + o];
}

// FC weight [512][4096] cast with column permute c*64+p -> p*64+c
__global__ void cast_perm_fc_kernel(const float* __restrict__ in, unsigned short* __restrict__ out)
{
  long i = (long)blockIdx.x * 256 + threadIdx.x;
  if (i >= 512L * 4096) return;
  int o = (int)(i >> 12);
  int r = (int)(i & 4095);
  int p = r >> 6, c = r & 63;
  out[i] = f2bf(in[((long)o << 12) + c * 64 + p]);
}

// conv weights [Cout][CIN][3][3] -> [9][NOUT][CINP] bf16 (zero-padded ic)
__global__ void wtap_kernel(const float* __restrict__ w, unsigned short* __restrict__ dst,
                            int CIN, int CINP, int NOUT)
{
  int i = blockIdx.x * 256 + threadIdx.x;
  int total = 9 * NOUT * CINP;
  if (i >= total) return;
  int t = i / (NOUT * CINP);
  int rem = i % (NOUT * CINP);
  int oc = rem / CINP, icp = rem % CINP;
  float v = icp < CIN ? w[(((long)oc * CIN + icp) * 3 + t / 3) * 3 + t % 3] : 0.f;
  dst[i] = f2bf(v);
}

// input [N][CIN][8][8] fp32 -> padded channel-last [N][10][10][CINP] bf16
// (buffer pre-zeroed: borders + ic-pad stay 0)
__global__ void pad_repack_kernel(const float* __restrict__ in, unsigned short* __restrict__ dst,
                                  int N, int CIN, int CINP)
{
  long i = (long)blockIdx.x * 256 + threadIdx.x;
  long total = (long)N * 64 * CINP;
  if (i >= total) return;
  int chp = (int)(i % CINP);
  long r = i / CINP;
  int p = (int)(r & 63);
  int n = (int)(r >> 6);
  float v = chp < CIN ? in[((long)n * CIN + chp) * 64 + p] : 0.f;
  int y = p >> 3, x = p & 7;
  dst[((long)n * 100 + (y + 1) * 10 + (x + 1)) * CINP + chp] = f2bf(v);
}

// ---------------- MFMA conv3x3 (implicit GEMM, 9 taps) ----------------------
// src: [N][10][10][CINP] bf16 padded channel-last. wt: [9][NOUT][CINP].
// Block = 128 pixel-rows (2 images), relu always.
// PADOUT: write interior of [N][10][10][NOUT] (pre-zeroed); else [N*64][NOUT].
template <int CINP, int NOUT, int PADOUT>
__global__ __launch_bounds__(256) void conv_mfma_kernel(
    const unsigned short* __restrict__ src, const unsigned short* __restrict__ wt,
    const float* __restrict__ bias, unsigned short* __restrict__ dst)
{
  constexpr int PITCH = CINP + 8;
  constexpr int WN = (NOUT == 64) ? 2 : 1;
  constexpr int ROWS = 128 / (4 / WN);
  constexpr int AI = ROWS / 16;
  constexpr int KC = CINP / 32;

  __shared__ __align__(16) unsigned short img[200 * PITCH];
  __shared__ __align__(16) unsigned short Bs[NOUT * PITCH];

  const int tid = threadIdx.x;
  const int lane = tid & 63;
  const int w = tid >> 6;
  const int wr = w / WN, wc = w % WN;
  const int lr = lane & 15, hi = lane >> 4;
  const int n0 = blockIdx.x * 2;

  {
    const unsigned short* g = src + (long)n0 * 100 * CINP;
    for (int e = tid * 8; e < 200 * CINP; e += 2048) {
      int row = e / CINP, k = e % CINP;
      *(u16x8*)(img + row * PITCH + k) = *(const u16x8*)(g + e);
    }
  }

  f32x4 acc[AI][2];
#pragma unroll
  for (int i = 0; i < AI; ++i)
#pragma unroll
    for (int j = 0; j < 2; ++j) acc[i][j] = (f32x4){0.f, 0.f, 0.f, 0.f};

#pragma unroll
  for (int t = 0; t < 9; ++t) {
    const int ky = t / 3, kx = t % 3;
    for (int e = tid * 8; e < NOUT * CINP; e += 2048) {
      int oc = e / CINP, k = e % CINP;
      *(u16x8*)(Bs + oc * PITCH + k) = *(const u16x8*)(wt + t * NOUT * CINP + e);
    }
    __syncthreads();
#pragma unroll
    for (int kc = 0; kc < KC; ++kc) {
      bf16x8 a[AI], b[2];
#pragma unroll
      for (int i = 0; i < AI; ++i) {
        int row = wr * ROWS + i * 16 + lr;
        int lrow = (row >> 6) * 100 + (((row >> 3) & 7) + ky) * 10 + (row & 7) + kx;
        a[i] = *(const bf16x8*)(img + lrow * PITCH + kc * 32 + hi * 8);
      }
#pragma unroll
      for (int j = 0; j < 2; ++j)
        b[j] = *(const bf16x8*)(Bs + (wc * 32 + j * 16 + lr) * PITCH + kc * 32 + hi * 8);
#pragma unroll
      for (int i = 0; i < AI; ++i)
#pragma unroll
        for (int j = 0; j < 2; ++j)
          acc[i][j] = __builtin_amdgcn_mfma_f32_16x16x32_bf16(a[i], b[j], acc[i][j], 0, 0, 0);
    }
    __syncthreads();
  }

  // C/D layout (m89): col = lane&15, row = (lane>>4)*4 + reg
#pragma unroll
  for (int j = 0; j < 2; ++j) {
    const int col = wc * 32 + j * 16 + lr;
    const float bv = bias[col];
#pragma unroll
    for (int i = 0; i < AI; ++i) {
#pragma unroll
      for (int v = 0; v < 4; ++v) {
        int row = wr * ROWS + i * 16 + hi * 4 + v;
        unsigned short o = f2bf(fmaxf(acc[i][j][v] + bv, 0.f));
        if (PADOUT) {
          int nl = row >> 6, y = (row >> 3) & 7, xx = row & 7;
          dst[((long)(n0 + nl) * 100 + (y + 1) * 10 + (xx + 1)) * NOUT + col] = o;
        } else {
          dst[((long)blockIdx.x * 128 + row) * NOUT + col] = o;
        }
      }
    }
  }
}

// ---------------- bf16 MFMA GEMM ---------------------------------------------
#define LDAP 72
__global__ __launch_bounds__(256) void gemm_bf16_kernel(
    const unsigned short* __restrict__ A, const unsigned short* __restrict__ B,
    const float* __restrict__ bias, float* __restrict__ C,
    int M, int N, int K, int relu, int obf, int splitK)
{
  __shared__ __align__(16) unsigned short As[128 * LDAP];
  __shared__ __align__(16) unsigned short Bs[128 * LDAP];

  const int tid = threadIdx.x;
  const int lane = tid & 63;
  const int w  = tid >> 6;
  const int wr = w >> 1, wc = w & 1;
  const int m0 = blockIdx.x * 128, n0 = blockIdx.y * 128;
  const int z  = blockIdx.z;

  const int lr = lane & 15;
  const int hi = lane >> 4;

  f32x4 acc[4][4] = {};

  const int r = tid >> 1;
  const int h = tid & 1;

  int mrow = m0 + r; if (mrow >= M) mrow = M - 1;
  const unsigned short* Ap = A + (long)mrow * K + h * 32;
  const unsigned short* Bp = B + (long)(n0 + r) * K + h * 32;
  unsigned short* Asd = As + r * LDAP + h * 32;
  unsigned short* Bsd = Bs + r * LDAP + h * 32;

  const int kLen = K / splitK;
  const int kBeg = z * kLen, kEnd = kBeg + kLen;

  for (int k0 = kBeg; k0 < kEnd; k0 += 64) {
#pragma unroll
    for (int i = 0; i < 4; ++i)
      *(u16x8*)(Asd + i * 8) = *(const u16x8*)(Ap + k0 + i * 8);
#pragma unroll
    for (int i = 0; i < 4; ++i)
      *(u16x8*)(Bsd + i * 8) = *(const u16x8*)(Bp + k0 + i * 8);
    __syncthreads();

#pragma unroll
    for (int kk = 0; kk < 2; ++kk) {
      const int kof = kk * 32 + hi * 8;
      bf16x8 a[4], b[4];
#pragma unroll
      for (int t = 0; t < 4; ++t)
        a[t] = *(const bf16x8*)(As + (wr * 64 + t * 16 + lr) * LDAP + kof);
#pragma unroll
      for (int t = 0; t < 4; ++t)
        b[t] = *(const bf16x8*)(Bs + (wc * 64 + t * 16 + lr) * LDAP + kof);
#pragma unroll
      for (int i = 0; i < 4; ++i)
#pragma unroll
        for (int j = 0; j < 4; ++j)
          acc[i][j] = __builtin_amdgcn_mfma_f32_16x16x32_bf16(a[i], b[j], acc[i][j], 0, 0, 0);
    }
    __syncthreads();
  }

#pragma unroll
  for (int j = 0; j < 4; ++j) {
    const int col = n0 + wc * 64 + j * 16 + lr;
    const float bv = (bias && z == 0) ? bias[col] : 0.f;
#pragma unroll
    for (int i = 0; i < 4; ++i) {
#pragma unroll
      for (int v = 0; v < 4; ++v) {
        int row = m0 + wr * 64 + i * 16 + hi * 4 + v;
        if (row < M) {
          float x = acc[i][j][v] + bv;
          if (splitK > 1) {
            atomicAdd(&C[(long)row * N + col], x);
          } else {
            if (relu) x = fmaxf(x, 0.f);
            if (obf) ((unsigned short*)C)[(long)row * N + col] = f2bf(x);
            else     C[(long)row * N + col] = x;
          }
        }
      }
    }
  }
}

static inline void gemm_bf(hipStream_t st, const unsigned short* A, const unsigned short* B,
                           const float* bias, float* C, int M, int N, int K,
                           int relu = 0, int obf = 0)
{
  dim3 g((M + 127) / 128, N / 128, 1);
  gemm_bf16_kernel<<<g, 256, 0, st>>>(A, B, bias, C, M, N, K, relu, obf, 1);
}

static inline void gemm_sk(hipStream_t st, const unsigned short* A, const unsigned short* B,
                           const float* bias, float* C, int M, int N, int K, int S)
{
  hipMemsetAsync(C, 0, (size_t)M * N * 4, st);
  dim3 g((M + 127) / 128, N / 128, S);
  gemm_bf16_kernel<<<g, 256, 0, st>>>(A, B, bias, C, M, N, K, 0, 0, S);
}

static inline void cast_bf(hipStream_t st, const float* in, unsigned short* out, long n)
{
  cast_bf16_kernel<<<(int)((n / 4 + 255) / 256), 256, 0, st>>>(in, out, n);
}

// ---------------- fused causal flash attention ------------------------------
__global__ __launch_bounds__(256) void attn_kernel(
    const unsigned short* __restrict__ Qkv, unsigned short* __restrict__ Ob)
{
  __shared__ __align__(16) unsigned short Kl[32 * 72];
  __shared__ __align__(16) unsigned short Vt[64 * 40];
  __shared__ __align__(16) unsigned short Pl[4][16 * 40];

  const int tid = threadIdx.x;
  const int lane = tid & 63;
  const int w = tid >> 6;
  const int lr = lane & 15, hi = lane >> 4;
  const int q0 = blockIdx.x * 64;
  const int bh = blockIdx.y;
  const int b = bh >> 3, h = bh & 7;
  const long baseq = (long)b * TT * 1536 + h * 64;
  const long baseo = (long)b * TT * 512 + h * 64;

  const int qrow = q0 + w * 16 + lr;
  const int qr_c = qrow < TT ? qrow : TT - 1;
  bf16x8 qf0 = *(const bf16x8*)(Qkv + baseq + (long)qr_c * 1536 + hi * 8);
  bf16x8 qf1 = *(const bf16x8*)(Qkv + baseq + (long)qr_c * 1536 + 32 + hi * 8);

  float m[4], l[4];
  f32x4 acc[4];
#pragma unroll
  for (int r = 0; r < 4; ++r) { m[r] = -1e30f; l[r] = 0.f; }
#pragma unroll
  for (int c = 0; c < 4; ++c) acc[c] = (f32x4){0.f, 0.f, 0.f, 0.f};

  const int qmax = min(q0 + 63, TT - 1);
  const int nkv = qmax + 1;

  for (int kv0 = 0; kv0 < nkv; kv0 += 32) {
    __syncthreads();
    {
      int e = tid * 8;
      int kv = e >> 6, d = e & 63;
      int skv = kv0 + kv; if (skv >= TT) skv = TT - 1;
      *(u16x8*)(Kl + kv * 72 + d) = *(const u16x8*)(Qkv + baseq + 512 + (long)skv * 1536 + d);
      u16x8 vv = *(const u16x8*)(Qkv + baseq + 1024 + (long)skv * 1536 + d);
#pragma unroll
      for (int j = 0; j < 8; ++j) Vt[(d + j) * 40 + kv] = vv[j];
    }
    __syncthreads();

    f32x4 s[2] = {};
#pragma unroll
    for (int t = 0; t < 2; ++t) {
      bf16x8 k0 = *(const bf16x8*)(Kl + (t * 16 + lr) * 72 + hi * 8);
      bf16x8 k1 = *(const bf16x8*)(Kl + (t * 16 + lr) * 72 + 32 + hi * 8);
      s[t] = __builtin_amdgcn_mfma_f32_16x16x32_bf16(qf0, k0, s[t], 0, 0, 0);
      s[t] = __builtin_amdgcn_mfma_f32_16x16x32_bf16(qf1, k1, s[t], 0, 0, 0);
    }

    const int qq = q0 + w * 16 + hi * 4;
#pragma unroll
    for (int r = 0; r < 4; ++r) {
      float v0 = s[0][r] * 0.125f;
      float v1 = s[1][r] * 0.125f;
      const int qr = qq + r;
      const int kvA = kv0 + lr, kvB = kv0 + 16 + lr;
      if (kvA > qr || kvA >= TT) v0 = -1e30f;
      if (kvB > qr || kvB >= TT) v1 = -1e30f;
      float rm = fmaxf(v0, v1);
      rm = fmaxf(rm, __shfl_xor(rm, 1));
      rm = fmaxf(rm, __shfl_xor(rm, 2));
      rm = fmaxf(rm, __shfl_xor(rm, 4));
      rm = fmaxf(rm, __shfl_xor(rm, 8));
      float mn = fmaxf(m[r], rm);
      float al = expf(m[r] - mn);
      float e0 = expf(v0 - mn);
      float e1 = expf(v1 - mn);
      float rs = e0 + e1;
      rs += __shfl_xor(rs, 1);
      rs += __shfl_xor(rs, 2);
      rs += __shfl_xor(rs, 4);
      rs += __shfl_xor(rs, 8);
      l[r] = l[r] * al + rs;
      m[r] = mn;
#pragma unroll
      for (int c = 0; c < 4; ++c) acc[c][r] *= al;
      Pl[w][(hi * 4 + r) * 40 + lr]      = f2bf(e0);
      Pl[w][(hi * 4 + r) * 40 + 16 + lr] = f2bf(e1);
    }

    bf16x8 pa = *(const bf16x8*)(&Pl[w][lr * 40 + hi * 8]);
#pragma unroll
    for (int c = 0; c < 4; ++c) {
      bf16x8 vf = *(const bf16x8*)(Vt + (c * 16 + lr) * 40 + hi * 8);
      acc[c] = __builtin_amdgcn_mfma_f32_16x16x32_bf16(pa, vf, acc[c], 0, 0, 0);
    }
  }

  float inv[4];
#pragma unroll
  for (int r = 0; r < 4; ++r) inv[r] = 1.0f / l[r];
#pragma unroll
  for (int c = 0; c < 4; ++c) {
#pragma unroll
    for (int r = 0; r < 4; ++r) {
      int qr = q0 + w * 16 + hi * 4 + r;
      if (qr < TT) Ob[baseo + (long)qr * 512 + c * 16 + lr] = f2bf(acc[c][r] * inv[r]);
    }
  }
}

// ---------------- transposed conv as dilated conv3x3 ------------------------
template <int CIN, int IH, int S, int OP, int OH>
__global__ __launch_bounds__(256) void convT_fast_kernel(
    const float* __restrict__ in, const float* __restrict__ w,
    const float* __restrict__ bias, float* __restrict__ out,
    int Cout, int relu, int inRelu)
{
  constexpr int DW = (IH - 1) * S + 3 + OP;
  constexpr int OCPB = 256 / OH;
  __shared__ float img[CIN * DW * DW];

  const int n = blockIdx.x;
  const int tid = threadIdx.x;
  for (int i = tid; i < CIN * DW * DW; i += 256) img[i] = 0.f;
  __syncthreads();
  const float* src = in + (long)n * CIN * IH * IH;
  for (int i = tid; i < CIN * IH * IH; i += 256) {
    int ic = i / (IH * IH), p = i % (IH * IH);
    int iy = p / IH, ix = p % IH;
    float v = src[i];
    if (inRelu) v = fmaxf(v, 0.f);
    img[ic * DW * DW + (1 + iy * S) * DW + (1 + ix * S)] = v;
  }
  __syncthreads();

  const int y  = tid % OH;
  const int oc = blockIdx.y * OCPB + tid / OH;
  if (oc >= Cout) return;

  float acc[OH];
#pragma unroll
  for (int x = 0; x < OH; ++x) acc[x] = bias[oc];

  for (int ic = 0; ic < CIN; ++ic) {
    const float* wp = w + ((long)ic * Cout + oc) * 9;
    float wr[9];
#pragma unroll
    for (int q = 0; q < 9; ++q) wr[q] = wp[8 - q];
    const float* ib = &img[ic * DW * DW + y * DW];
#pragma unroll
    for (int ky = 0; ky < 3; ++ky) {
      const float* r = ib + ky * DW;
      float c0 = r[0], c1 = r[1];
#pragma unroll
      for (int x = 0; x < OH; ++x) {
        float c2 = r[x + 2];
        acc[x] = fmaf(c0, wr[ky * 3 + 0],
                 fmaf(c1, wr[ky * 3 + 1],
                 fmaf(c2, wr[ky * 3 + 2], acc[x])));
        c0 = c1; c1 = c2;
      }
    }
  }
  float* dst = out + ((long)n * Cout + oc) * OH * OH + y * OH;
#pragma unroll
  for (int x = 0; x < OH; ++x) dst[x] = relu ? fmaxf(acc[x], 0.f) : acc[x];
}

// ---------------- LayerNorm (D=512), residual add, dual fp32+bf16 out -------
__device__ __forceinline__ float blockReduceSum256(float v)
{
  __shared__ float sb[4];
  int lane = threadIdx.x & 63, wid = threadIdx.x >> 6;
#pragma unroll
  for (int o = 32; o; o >>= 1) v += __shfl_down(v, o);
  __syncthreads();
  if (lane == 0) sb[wid] = v;
  __syncthreads();
  return sb[0] + sb[1] + sb[2] + sb[3];
}

__global__ __launch_bounds__(256) void add_ln_kernel(
    const float* __restrict__ a, const float* __restrict__ b,
    const float* __restrict__ w, const float* __restrict__ bb,
    float* __restrict__ out, unsigned short* __restrict__ outbf)
{
  long row = blockIdx.x;
  const float* pa = a + row * 512;
  float x0 = pa[threadIdx.x], x1 = pa[threadIdx.x + 256];
  if (b) {
    const float* pb = b + row * 512;
    x0 += pb[threadIdx.x]; x1 += pb[threadIdx.x + 256];
  }
  float mean = blockReduceSum256(x0 + x1) * (1.f / 512.f);
  float d0 = x0 - mean, d1 = x1 - mean;
  float var = blockReduceSum256(d0 * d0 + d1 * d1) * (1.f / 512.f);
  float inv = 1.0f / sqrtf(var + 1e-5f);
  float v0 = d0 * inv * w[threadIdx.x] + bb[threadIdx.x];
  float v1 = d1 * inv * w[threadIdx.x + 256] + bb[threadIdx.x + 256];
  float* po = out + row * 512;
  po[threadIdx.x]       = v0;
  po[threadIdx.x + 256] = v1;
  if (outbf) {
    outbf[row * 512 + threadIdx.x]       = f2bf(v0);
    outbf[row * 512 + threadIdx.x + 256] = f2bf(v1);
  }
}

// ---------------- small elementwise kernels ---------------------------------
__global__ void lin1_relu_bf_kernel(const float* __restrict__ x, const float* __restrict__ w,
                                    const float* __restrict__ b, unsigned short* __restrict__ out,
                                    long total)
{
  long idx = (long)blockIdx.x * 256 + threadIdx.x;
  if (idx >= total) return;
  int d = idx & 511; long r = idx >> 9;
  out[idx] = f2bf(fmaxf(fmaf(x[r], w[d], b[d]), 0.f));
}

__global__ void lin1_relu_int_bf_kernel(const int* __restrict__ x, const float* __restrict__ w,
                                        const float* __restrict__ b, unsigned short* __restrict__ out,
                                        long total)
{
  long idx = (long)blockIdx.x * 256 + threadIdx.x;
  if (idx >= total) return;
  int d = idx & 511; long r = idx >> 9;
  out[idx] = f2bf(fmaxf(fmaf((float)x[r], w[d], b[d]), 0.f));
}

__global__ void build_comb_bf_kernel(const float* __restrict__ r, const float* __restrict__ s,
                                     const float* __restrict__ a, const float* __restrict__ t,
                                     unsigned short* __restrict__ comb)
{
  long idx = (long)blockIdx.x * 256 + threadIdx.x;
  if (idx >= (long)8 * TT * 512) return;
  int d = idx & 511;
  long rr = idx >> 9;
  int tok = (int)(rr % TT);
  int b   = (int)(rr / TT);
  int grp = tok / 3, ph = tok % 3;
  float te = t[((long)b * 128 + grp) * 512 + d];
  float v;
  if (ph == 0)      v = r[((long)b * 128 + grp) * 512 + d] + te;
  else if (ph == 1) v = s[((long)b * 128 + grp) * 512 + d] + te;
  else              v = a[((long)b * 127 + grp) * 512 + d] + te;
  comb[idx] = f2bf(v);
}

__global__ void gather3_kernel(const float* __restrict__ x, float* __restrict__ out,
                               int offset, int count)
{
  long idx = (long)blockIdx.x * 256 + threadIdx.x;
  long total = (long)8 * count * 512;
  if (idx >= total) return;
  int d = idx & 511;
  long r = idx >> 9;
  int i = (int)(r % count);
  int b = (int)(r / count);
  out[idx] = x[((long)b * TT + offset + 3 * i) * 512 + d];
}

__global__ __launch_bounds__(256) void reward_kernel(const float* __restrict__ x,
                                                     const float* __restrict__ w,
                                                     const float* __restrict__ b,
                                                     float* __restrict__ out, int rows)
{
  int row = blockIdx.x * 4 + (threadIdx.x >> 6);
  int lane = threadIdx.x & 63;
  if (row >= rows) return;
  const float* p = x + (long)row * 512;
  float s = 0.f;
  for (int j = lane; j < 512; j += 64) s = fmaf(p[j], w[j], s);
#pragma unroll
  for (int o = 32; o; o >>= 1) s += __shfl_xor(s, o);
  if (lane == 0) out[row] = s + b[0];
}

// ---------------------------------------------------------------------------
extern "C" void kernel_launch(void* const* d_in, const int* in_sizes, int n_in,
                              void* d_out, int out_size, void* d_ws, size_t ws_size,
                              hipStream_t stream)
{
  const float* states  = (const float*)d_in[0];
  const float* rtgs    = (const float*)d_in[1];
  const int*   tsteps  = (const int*)d_in[2];
  const float* actions = (const float*)d_in[3];
  // d_in[4] mask: tril, hardcoded causal
  const float* se_c1w = (const float*)d_in[5];  const float* se_c1b = (const float*)d_in[6];
  const float* se_c2w = (const float*)d_in[7];  const float* se_c2b = (const float*)d_in[8];
  const float* se_c3w = (const float*)d_in[9];  const float* se_c3b = (const float*)d_in[10];
  const float* se_fcw = (const float*)d_in[11]; const float* se_fcb = (const float*)d_in[12];
  const float* se_lnw = (const float*)d_in[13]; const float* se_lnb = (const float*)d_in[14];
  const float* ae_c1w = (const float*)d_in[15]; const float* ae_c1b = (const float*)d_in[16];
  const float* ae_c2w = (const float*)d_in[17]; const float* ae_c2b = (const float*)d_in[18];
  const float* ae_c3w = (const float*)d_in[19]; const float* ae_c3b = (const float*)d_in[20];
  const float* ae_fcw = (const float*)d_in[21]; const float* ae_fcb = (const float*)d_in[22];
  const float* ae_lnw = (const float*)d_in[23]; const float* ae_lnb = (const float*)d_in[24];
  const float* rtg_w1 = (const float*)d_in[25]; const float* rtg_b1 = (const float*)d_in[26];
  const float* rtg_w2 = (const float*)d_in[27]; const float* rtg_b2 = (const float*)d_in[28];
  const float* rtg_lnw= (const float*)d_in[29]; const float* rtg_lnb= (const float*)d_in[30];
  const float* ts_w1  = (const float*)d_in[31]; const float* ts_b1  = (const float*)d_in[32];
  const float* ts_w2  = (const float*)d_in[33]; const float* ts_b2  = (const float*)d_in[34];
  const float* ts_lnw = (const float*)d_in[35]; const float* ts_lnb = (const float*)d_in[36];
  const float* ip_w   = (const float*)d_in[37]; const float* ip_b   = (const float*)d_in[38];
  const float* lyr_wq = (const float*)d_in[39]; const float* lyr_bq = (const float*)d_in[40];
  const float* lyr_wk = (const float*)d_in[41]; const float* lyr_bk = (const float*)d_in[42];
  const float* lyr_wv = (const float*)d_in[43]; const float* lyr_bv = (const float*)d_in[44];
  const float* lyr_wo = (const float*)d_in[45]; const float* lyr_bo = (const float*)d_in[46];
  const float* lyr_f1w= (const float*)d_in[47]; const float* lyr_f1b= (const float*)d_in[48];
  const float* lyr_f2w= (const float*)d_in[49]; const float* lyr_f2b= (const float*)d_in[50];
  const float* lyr_l1w= (const float*)d_in[51]; const float* lyr_l1b= (const float*)d_in[52];
  const float* lyr_l2w= (const float*)d_in[53]; const float* lyr_l2b= (const float*)d_in[54];
  const float* ad_fcw = (const float*)d_in[55]; const float* ad_fcb = (const float*)d_in[56];
  const float* ad_w1  = (const float*)d_in[57]; const float* ad_b1  = (const float*)d_in[58];
  const float* ad_w2  = (const float*)d_in[59]; const float* ad_b2  = (const float*)d_in[60];
  const float* ad_w3  = (const float*)d_in[61]; const float* ad_b3  = (const float*)d_in[62];
  const float* sd_fcw = (const float*)d_in[63]; const float* sd_fcb = (const float*)d_in[64];
  const float* sd_w1  = (const float*)d_in[65]; const float* sd_b1  = (const float*)d_in[66];
  const float* sd_w2  = (const float*)d_in[67]; const float* sd_b2  = (const float*)d_in[68];
  const float* sd_w3  = (const float*)d_in[69]; const float* sd_b3  = (const float*)d_in[70];
  const float* rp_w   = (const float*)d_in[71]; const float* rp_b   = (const float*)d_in[72];

  float* ws = (float*)d_ws;
  long off = 0;
  auto alloc = [&](long n) { float* p = ws + off; off += n; return p; };

  float* region = alloc(10485760);           // conv (as bf16) / decoder scratch
  float* s_emb = alloc(524288);
  float* a_emb = alloc(520192);
  float* r_emb = alloc(524288);
  float* t_emb = alloc(524288);
  float* etmp  = alloc(524288);
  float* xa = alloc(1568768);
  float* xb = alloc(1568768);
  float* t2 = alloc(1568768);
  float* qkvB = alloc(9216);                 // merged QKV bias [6][1536]

  unsigned short* bws = (unsigned short*)(ws + off);
  long boff = 0;
  auto ballo = [&](long n) { unsigned short* p = bws + boff; boff += n; return p; };
  unsigned short* ipW   = ballo(262144);
  unsigned short* wqkvW = ballo(6L * 786432);
  unsigned short* woW   = ballo(6L * 262144);
  unsigned short* f1W   = ballo(6L * 1048576);
  unsigned short* f2W   = ballo(6L * 1048576);
  unsigned short* seWp  = ballo(2097152);    // permuted FC weights
  unsigned short* aeWp  = ballo(2097152);
  unsigned short* rtgW  = ballo(262144);
  unsigned short* tsW   = ballo(262144);
  unsigned short* adW   = ballo(262144);
  unsigned short* sdW   = ballo(262144);
  unsigned short* wtSE1 = ballo(9216);       // [9][32][32]
  unsigned short* wtSE2 = ballo(18432);      // [9][64][32]
  unsigned short* wtSE3 = ballo(36864);      // [9][64][64]
  unsigned short* wtAE1 = ballo(27648);      // [9][32][96]
  unsigned short* wtAE2 = ballo(18432);
  unsigned short* wtAE3 = ballo(36864);
  unsigned short* qkvbf = ballo(4706304);    // [BT][1536]
  unsigned short* aobf  = ballo(1568768);
  unsigned short* xbfA  = ballo(1568768);
  unsigned short* xbfB  = ballo(1568768);
  unsigned short* ffhbf = ballo(6275072);    // FFN hidden / conv3 out (aliased)
  unsigned short* abuf  = ballo(6275072);    // general bf16 scratch

  // conv padded buffers alias 'region' (dead before decoders reuse it)
  unsigned short* P1  = (unsigned short*)region;     // <= 1016*100*96 = 9.754M
  unsigned short* Po1 = P1 + 9830400;                // [N][10][10][32]: 3.277M
  unsigned short* Po2 = Po1 + 3276800;               // [N][10][10][64]: 6.554M
  unsigned short* c3o = ffhbf;                       // [N*64][64]: 4.194M

  const long BT = (long)8 * TT;

  // ---------------- weight pre-casts / repacks ----------------
  cast_bf(stream, ip_w,    ipW,  262144);
  merge_qkv_w_kernel<<<(int)((6L * 786432 / 4 + 255) / 256), 256, 0, stream>>>(lyr_wq, lyr_wk, lyr_wv, wqkvW);
  merge_qkv_b_kernel<<<(6 * 1536 + 255) / 256, 256, 0, stream>>>(lyr_bq, lyr_bk, lyr_bv, qkvB);
  cast_bf(stream, lyr_wo,  woW,  6L * 262144);
  cast_bf(stream, lyr_f1w, f1W,  6L * 1048576);
  cast_bf(stream, lyr_f2w, f2W,  6L * 1048576);
  cast_perm_fc_kernel<<<(int)((512L * 4096 + 255) / 256), 256, 0, stream>>>(se_fcw, seWp);
  cast_perm_fc_kernel<<<(int)((512L * 4096 + 255) / 256), 256, 0, stream>>>(ae_fcw, aeWp);
  cast_bf(stream, rtg_w2,  rtgW, 262144);
  cast_bf(stream, ts_w2,   tsW,  262144);
  cast_bf(stream, ad_fcw,  adW,  262144);
  cast_bf(stream, sd_fcw,  sdW,  262144);
  wtap_kernel<<<(9 * 32 * 32 + 255) / 256, 256, 0, stream>>>(se_c1w, wtSE1, 14, 32, 32);
  wtap_kernel<<<(9 * 64 * 32 + 255) / 256, 256, 0, stream>>>(se_c2w, wtSE2, 32, 32, 64);
  wtap_kernel<<<(9 * 64 * 64 + 255) / 256, 256, 0, stream>>>(se_c3w, wtSE3, 64, 64, 64);
  wtap_kernel<<<(9 * 32 * 96 + 255) / 256, 256, 0, stream>>>(ae_c1w, wtAE1, 73, 96, 32);
  wtap_kernel<<<(9 * 64 * 32 + 255) / 256, 256, 0, stream>>>(ae_c2w, wtAE2, 32, 32, 64);
  wtap_kernel<<<(9 * 64 * 64 + 255) / 256, 256, 0, stream>>>(ae_c3w, wtAE3, 64, 64, 64);

  // ---------------- state encoder (MFMA convs) ----------------
  hipMemsetAsync(P1, 0, 1024L * 100 * 32 * 2, stream);
  pad_repack_kernel<<<(int)((1024L * 64 * 32 + 255) / 256), 256, 0, stream>>>(states, P1, 1024, 14, 32);
  hipMemsetAsync(Po1, 0, 1024L * 100 * 32 * 2, stream);
  conv_mfma_kernel<32, 32, 1><<<512, 256, 0, stream>>>(P1, wtSE1, se_c1b, Po1);
  hipMemsetAsync(Po2, 0, 1024L * 100 * 64 * 2, stream);
  conv_mfma_kernel<32, 64, 1><<<512, 256, 0, stream>>>(Po1, wtSE2, se_c2b, Po2);
  conv_mfma_kernel<64, 64, 0><<<512, 256, 0, stream>>>(Po2, wtSE3, se_c3b, c3o);
  gemm_sk(stream, c3o, seWp, se_fcb, etmp, 1024, 512, 4096, 8);
  add_ln_kernel<<<1024, 256, 0, stream>>>(etmp, nullptr, se_lnw, se_lnb, s_emb, nullptr);

  // ---------------- action encoder ----------------
  hipMemsetAsync(P1, 0, 1016L * 100 * 96 * 2, stream);
  pad_repack_kernel<<<(int)((1016L * 64 * 96 + 255) / 256), 256, 0, stream>>>(actions, P1, 1016, 73, 96);
  hipMemsetAsync(Po1, 0, 1016L * 100 * 32 * 2, stream);
  conv_mfma_kernel<96, 32, 1><<<508, 256, 0, stream>>>(P1, wtAE1, ae_c1b, Po1);
  hipMemsetAsync(Po2, 0, 1016L * 100 * 64 * 2, stream);
  conv_mfma_kernel<32, 64, 1><<<508, 256, 0, stream>>>(Po1, wtAE2, ae_c2b, Po2);
  conv_mfma_kernel<64, 64, 0><<<508, 256, 0, stream>>>(Po2, wtAE3, ae_c3b, c3o);
  gemm_sk(stream, c3o, aeWp, ae_fcb, etmp, 1016, 512, 4096, 8);
  add_ln_kernel<<<1016, 256, 0, stream>>>(etmp, nullptr, ae_lnw, ae_lnb, a_emb, nullptr);

  // ---------------- rtg / timestep MLPs ----------------
  lin1_relu_bf_kernel<<<(1024 * 512 + 255) / 256, 256, 0, stream>>>(rtgs, rtg_w1, rtg_b1, abuf, 1024 * 512);
  gemm_sk(stream, abuf, rtgW, rtg_b2, etmp, 1024, 512, 512, 8);
  add_ln_kernel<<<1024, 256, 0, stream>>>(etmp, nullptr, rtg_lnw, rtg_lnb, r_emb, nullptr);

  lin1_relu_int_bf_kernel<<<(1024 * 512 + 255) / 256, 256, 0, stream>>>(tsteps, ts_w1, ts_b1, abuf, 1024 * 512);
  gemm_sk(stream, abuf, tsW, ts_b2, etmp, 1024, 512, 512, 8);
  add_ln_kernel<<<1024, 256, 0, stream>>>(etmp, nullptr, ts_lnw, ts_lnb, t_emb, nullptr);

  build_comb_bf_kernel<<<(int)((8L * TT * 512 + 255) / 256), 256, 0, stream>>>(r_emb, s_emb, a_emb, t_emb, abuf);
  gemm_sk(stream, abuf, ipW, ip_b, xa, (int)BT, 512, 512, 4);
  cast_bf(stream, xa, xbfA, BT * 512);

  // ---------------- transformer layers ----------------
  for (int l = 0; l < 6; ++l) {
    const unsigned short* wqkv = wqkvW + (long)l * 786432;
    const float* bqkv = qkvB + (long)l * 1536;
    const unsigned short* wo = woW + (long)l * 262144; const float* bo = lyr_bo + (long)l * 512;
    const unsigned short* f1w = f1W + (long)l * 1048576; const float* f1b = lyr_f1b + (long)l * 2048;
    const unsigned short* f2w = f2W + (long)l * 1048576; const float* f2b = lyr_f2b + (long)l * 512;
    const float* l1w = lyr_l1w + (long)l * 512; const float* l1b = lyr_l1b + (long)l * 512;
    const float* l2w = lyr_l2w + (long)l * 512; const float* l2b = lyr_l2b + (long)l * 512;

    gemm_bf(stream, xbfA, wqkv, bqkv, (float*)qkvbf, (int)BT, 1536, 512, 0, 1);
    attn_kernel<<<dim3(6, 64), 256, 0, stream>>>(qkvbf, aobf);
    gemm_sk(stream, aobf, wo, bo, t2, (int)BT, 512, 512, 4);
    add_ln_kernel<<<(int)BT, 256, 0, stream>>>(xa, t2, l1w, l1b, xb, xbfB);
    gemm_bf(stream, xbfB, f1w, f1b, (float*)ffhbf, (int)BT, 2048, 512, 1, 1);
    gemm_sk(stream, ffhbf, f2w, f2b, t2, (int)BT, 512, 2048, 8);
    add_ln_kernel<<<(int)BT, 256, 0, stream>>>(xb, t2, l2w, l2b, xa, xbfA);
  }

  // ---------------- decoders ----------------
  float* outp = (float*)d_out;
  float* act_out = outp;              // 8*128*73*64 = 4,784,128
  float* st_out  = outp + 4784128;    // 8*128*14*64 = 917,504
  float* rw_out  = outp + 5701632;    // 8*127 = 1016

  float* za  = region;
  float* zfc = region + 524288;
  float* dh1 = region + 1048576;
  float* dh2 = region + 2097152;

  gather3_kernel<<<(1024 * 512 + 255) / 256, 256, 0, stream>>>(xa, za, 1, 128);
  cast_bf(stream, za, abuf, 1024L * 512);
  gemm_sk(stream, abuf, adW, ad_fcb, zfc, 1024, 512, 512, 8);   // relu folded into convT load
  convT_fast_kernel<128, 2, 2, 1, 4><<<dim3(1024, 1), 256, 0, stream>>>(zfc, ad_w1, ad_b1, dh1, 64, 1, 1);
  convT_fast_kernel<64, 4, 2, 1, 8><<<dim3(1024, 1), 256, 0, stream>>>(dh1, ad_w2, ad_b2, dh2, 32, 1, 0);
  convT_fast_kernel<32, 8, 1, 0, 8><<<dim3(1024, 3), 256, 0, stream>>>(dh2, ad_w3, ad_b3, act_out, 73, 0, 0);

  gather3_kernel<<<(1024 * 512 + 255) / 256, 256, 0, stream>>>(xa, za, 0, 128);
  cast_bf(stream, za, abuf, 1024L * 512);
  gemm_sk(stream, abuf, sdW, sd_fcb, zfc, 1024, 512, 512, 8);
  convT_fast_kernel<128, 2, 2, 1, 4><<<dim3(1024, 1), 256, 0, stream>>>(zfc, sd_w1, sd_b1, dh1, 64, 1, 1);
  convT_fast_kernel<64, 4, 2, 1, 8><<<dim3(1024, 1), 256, 0, stream>>>(dh1, sd_w2, sd_b2, dh2, 32, 1, 0);
  convT_fast_kernel<32, 8, 1, 0, 8><<<dim3(1024, 1), 256, 0, stream>>>(dh2, sd_w3, sd_b3, st_out, 14, 0, 0);

  gather3_kernel<<<(1016 * 512 + 255) / 256, 256, 0, stream>>>(xa, za, 2, 127);
  reward_kernel<<<(1016 + 3) / 4, 256, 0, stream>>>(za, rp_w, rp_b, rw_out, 1016);
}